// Round 1
// baseline (2401.762 us; speedup 1.0000x reference)
//
#include <hip/hip_runtime.h>
#include <hip/hip_bf16.h>
#include <cstdint>
#include <cstddef>

// ---------- types / helpers ----------
typedef __attribute__((ext_vector_type(8))) short short8;   // 8 x bf16 (4 VGPRs)
typedef __attribute__((ext_vector_type(4))) float floatx4;  // mfma accumulator

__device__ inline float bf2f(unsigned short u) {
  union { unsigned int i; float f; } v; v.i = ((unsigned int)u) << 16; return v.f;
}
__device__ inline unsigned short f2bf(float f) {
  union { float f; unsigned int i; } v; v.f = f;
  unsigned int u = v.i;
  return (unsigned short)((u + 0x7FFFu + ((u >> 16) & 1u)) >> 16); // RNE
}
__device__ inline short8 ld8(const unsigned short* p) {
  return *reinterpret_cast<const short8*>(p); // 16B aligned everywhere we use it
}
__device__ inline float sigmoidf_(float x) { return 1.0f / (1.0f + expf(-x)); }

// ---------- workspace layout (bytes) ----------
static const size_t OFF_WIH   = 0;          // 2,097,152  bf16 w_ih (2048,512)
static const size_t OFF_WHH   = 2097152;    // 2,097,152  bf16 w_hh (2048,512)
static const size_t OFF_VPROJ = 4194304;    // 1,048,576  bf16 (1024,512)
static const size_t OFF_VISE  = 5242880;    //   524,288  bf16 (1024,256)
static const size_t OFF_HS    = 5767168;    // 1,310,720  bf16 (1280,512) row=b*20+t
static const size_t OFF_XIN   = 7077888;    //    65,536  bf16 (64,512)
static const size_t OFF_H0    = 7143424;    //    65,536  bf16 (64,512)
static const size_t OFF_H1    = 7208960;    //    65,536  bf16 (64,512)
static const size_t OFF_CT    = 7274496;    //   131,072  f32  (512,64)
static const size_t OFF_W1PAD = 7405568;    //     4,096  bf16 (64,32)
static const size_t OFF_CW2   = 7409664;    //   147,456  bf16 (128,576)
static const size_t OFF_CW3   = 7557120;    //   589,824  bf16 (256,1152)
static const size_t OFF_CW4   = 8146944;    // 2,359,296  bf16 (512,2304)
static const size_t OFF_PRJW  = 10506240;   //   262,144  bf16 (256,512)
static const size_t OFF_ATWV  = 10768384;   //   262,144  bf16 (512,256)
static const size_t OFF_ACT1  = 11030528;   // 8,388,608  bf16 (64,64,32,32); act3 reuses
static const size_t OFF_ACT3  = 11030528;   // 2,097,152  bf16 (64,256,8,8)
static const size_t OFF_ACT2  = 19419136;   // 4,194,304  bf16 (64,128,16,16); act4+visA reuse
static const size_t OFF_ACT4  = 19419136;   // 1,048,576  bf16 (64,512,4,4)
static const size_t OFF_VISA  = 20467712;   // 1,048,576  bf16 (1024,512)
static const size_t OFF_COL   = 23613440;   // 4,718,592  small im2col arena / out_w chunks
static const size_t OFF_BAR   = 28332032;   //       256  grid-barrier state (cnt,gen)
static const size_t OFF_BIG   = 28332288;   // optional: 32,768,000 big arena (conv2 col 18.9MB / out_w bf16 32.8MB)
static const size_t NEED_BIG  = OFF_BIG + 32768000; // 61,100,288

// ---------- device-scope grid barrier (all blocks co-resident: grid=64 <= 256 CUs) ----------
__device__ inline void gbar(unsigned int* bar, unsigned int nblk) {
  __syncthreads();
  if (threadIdx.x == 0) {
    __threadfence();  // publish this block's global writes (agent-scope wb)
    unsigned int g = __hip_atomic_load(bar + 1, __ATOMIC_RELAXED, __HIP_MEMORY_SCOPE_AGENT);
    unsigned int a = __hip_atomic_fetch_add(bar, 1u, __ATOMIC_ACQ_REL, __HIP_MEMORY_SCOPE_AGENT);
    if (a == nblk - 1) {
      __hip_atomic_store(bar, 0u, __ATOMIC_RELAXED, __HIP_MEMORY_SCOPE_AGENT);
      __hip_atomic_store(bar + 1, g + 1u, __ATOMIC_RELEASE, __HIP_MEMORY_SCOPE_AGENT);
    } else {
      while (__hip_atomic_load(bar + 1, __ATOMIC_ACQUIRE, __HIP_MEMORY_SCOPE_AGENT) == g)
        __builtin_amdgcn_s_sleep(1);
    }
    __threadfence();  // acquire others' writes (agent-scope inv)
  }
  __syncthreads();
}

// ---------- f32 -> bf16 bulk convert (4 elems/thread) ----------
__global__ void cvt_k(const float* __restrict__ s, unsigned short* __restrict__ d, int n4)
{
  int i = blockIdx.x * 256 + threadIdx.x;
  if (i < n4) {
    float4 v = reinterpret_cast<const float4*>(s)[i];
    ushort4 o;
    o.x = f2bf(v.x); o.y = f2bf(v.y); o.z = f2bf(v.z); o.w = f2bf(v.w);
    reinterpret_cast<ushort4*>(d)[i] = o;
  }
}

// ---------- fused multi-segment f32 -> bf16 convert (7 weight tensors, one dispatch) ----------
struct CvtArgs {
  const float* s[7];
  unsigned short* d[7];
  int cum[8];  // cumulative float4 counts, cum[0]=0
};
__global__ void cvtall_k(CvtArgs a)
{
  int i = blockIdx.x * 256 + threadIdx.x;
  if (i >= a.cum[7]) return;
  int seg = 0;
  while (seg < 6 && i >= a.cum[seg + 1]) ++seg;
  int j = i - a.cum[seg];
  float4 v = reinterpret_cast<const float4*>(a.s[seg])[j];
  ushort4 o;
  o.x = f2bf(v.x); o.y = f2bf(v.y); o.z = f2bf(v.z); o.w = f2bf(v.w);
  reinterpret_cast<ushort4*>(a.d[seg])[j] = o;
}

// ---------- init: conv1 weight K-pad (f32->bf16), zero h0 / c / barrier ----------
__global__ void init_k(const float* __restrict__ conv1_w, unsigned short* __restrict__ w1pad,
                       unsigned short* __restrict__ h0, float* __restrict__ cT,
                       unsigned int* __restrict__ bar)
{
  int i = blockIdx.x * 256 + threadIdx.x;               // grid covers 32768
  if (i < 64 * 32) {
    int co = i >> 5, k = i & 31;
    w1pad[i] = (k < 27) ? f2bf(conv1_w[co * 27 + k]) : (unsigned short)0;
  }
  if (i < 64 * 512) h0[i] = 0;
  if (i < 512 * 64) cT[i] = 0.0f;
  if (i < 64) bar[i] = 0u;   // reset grid-barrier state every replay
}

// ---------- conv1 im2col: one thread per (pixel,k) element; coalesced 512B/wave writes ----------
__global__ void im2col1_k(const float* __restrict__ in, unsigned short* __restrict__ col)
{
  int o = blockIdx.x * 256 + threadIdx.x;   // 65536 pixels * 32 Kpad = 2,097,152
  int n = o >> 5, k = o & 31;
  unsigned short v = 0;
  if (k < 27) {
    int b = n >> 10, y = (n >> 5) & 31, x = n & 31;
    int ci = k / 9, r9 = k - ci * 9, ky = r9 / 3, kx = r9 - ky * 3;
    int iy = 2 * y - 1 + ky, ix = 2 * x - 1 + kx;
    if (iy >= 0 && iy < 64 && ix >= 0 && ix < 64)
      v = f2bf(in[(((size_t)b * 3 + ci) << 12) + (iy << 6) + ix]);
  }
  col[o] = v;
}

// ---------- im2col (chunked): col[local n][k] bf16; global n = n0 + blockIdx.x ----------
__global__ void im2col_k(const unsigned short* __restrict__ in, unsigned short* __restrict__ col,
                         int Cin, int Hin, int Win, int Kreal, int Kpad, int lgHW, int lgW,
                         int n0)
{
  const int ng = n0 + blockIdx.x;
  const int b = ng >> lgHW;
  const int yx = ng & ((1 << lgHW) - 1);
  const int y = yx >> lgW;
  const int x = yx & ((1 << lgW) - 1);
  const int iy0 = 2 * y - 1;
  const int ix0 = 2 * x - 1;
  for (int k = threadIdx.x; k < Kpad; k += blockDim.x) {
    unsigned short v = 0;
    if (k < Kreal) {
      int ci = k / 9;
      int r9 = k - ci * 9;
      int ky = r9 / 3;
      int kx = r9 - ky * 3;
      int iy = iy0 + ky, ix = ix0 + kx;
      if (iy >= 0 && iy < Hin && ix >= 0 && ix < Win) {
        size_t idx = (((size_t)b * Cin + ci) * Hin + iy) * Win + ix;
        v = in[idx];
      }
    }
    col[(size_t)blockIdx.x * Kpad + k] = v;
  }
}

// ---------- gather visual: visA[(b*16+r)*512+c] = act4[b][c][r] ----------
__global__ void visa_k(const unsigned short* __restrict__ act4, unsigned short* __restrict__ visA)
{
  int o = blockIdx.x * 256 + threadIdx.x;   // 524288 total
  int c = o & 511, br = o >> 9;
  int b = br >> 4, r = br & 15;
  visA[o] = act4[(((size_t)b * 512 + c) << 4) + r];
}

// ---------- generic MFMA GEMM: C(M,N) = A(M,K) * B(N,K)^T, A/B bf16 ----------
// EPI 0: conv epilogue  relu(C*scale[m]+shift[m]) -> bf16 scatter (b,Cout,HW), n_base global
// EPI 1: bf16 out[m*N+n] = C + biasN[n]
// EPI 2: f32  out[m*ldOut + n_base + n] = C + biasN[n_base+n]
template<int EPI>
__global__ __launch_bounds__(256)
void gemm_k(const unsigned short* __restrict__ A, const unsigned short* __restrict__ B,
            int K, int N, void* __restrict__ outp,
            const float* __restrict__ cb, const float* __restrict__ bg,
            const float* __restrict__ bb, const float* __restrict__ bm,
            const float* __restrict__ bv, int Cout, int lgHW,
            const float* __restrict__ biasN, int n_base, int ldOut)
{
  const int w   = threadIdx.x >> 6;
  const int l   = threadIdx.x & 63;
  const int l15 = l & 15;
  const int q   = l >> 4;
  const int m0  = blockIdx.y * 64;
  const int n0  = blockIdx.x * 256 + w * 64;
  const unsigned short* Ap = A + (size_t)(m0 + l15) * K + q * 8;
  const unsigned short* Bp = B + (size_t)(n0 + l15) * K + q * 8;

  floatx4 acc[4][4];
  #pragma unroll
  for (int i = 0; i < 4; i++)
    #pragma unroll
    for (int j = 0; j < 4; j++)
      acc[i][j] = (floatx4){0.f, 0.f, 0.f, 0.f};

  for (int kc = 0; kc < K; kc += 32) {
    short8 a0 = ld8(Ap + kc);
    short8 a1 = ld8(Ap + (size_t)16 * K + kc);
    short8 a2 = ld8(Ap + (size_t)32 * K + kc);
    short8 a3 = ld8(Ap + (size_t)48 * K + kc);
    #pragma unroll
    for (int nf = 0; nf < 4; nf++) {
      short8 bf = ld8(Bp + (size_t)(nf * 16) * K + kc);
      acc[0][nf] = __builtin_amdgcn_mfma_f32_16x16x32_bf16(a0, bf, acc[0][nf], 0, 0, 0);
      acc[1][nf] = __builtin_amdgcn_mfma_f32_16x16x32_bf16(a1, bf, acc[1][nf], 0, 0, 0);
      acc[2][nf] = __builtin_amdgcn_mfma_f32_16x16x32_bf16(a2, bf, acc[2][nf], 0, 0, 0);
      acc[3][nf] = __builtin_amdgcn_mfma_f32_16x16x32_bf16(a3, bf, acc[3][nf], 0, 0, 0);
    }
  }
  // C/D layout (verified m89/m91): col = lane&15, row = (lane>>4)*4 + reg
  #pragma unroll
  for (int mf = 0; mf < 4; mf++) {
    #pragma unroll
    for (int r = 0; r < 4; r++) {
      int m = m0 + mf * 16 + q * 4 + r;
      float scale = 1.0f, shift = 0.0f;
      if (EPI == 0) {
        float inv = bg[m] / sqrtf(bv[m] + 1e-5f);
        scale = inv;
        shift = (cb[m] - bm[m]) * inv + bb[m];
      }
      #pragma unroll
      for (int nf = 0; nf < 4; nf++) {
        int n = n0 + nf * 16 + l15;
        float c = acc[mf][nf][r];
        if (EPI == 0) {
          c = fmaxf(c * scale + shift, 0.0f);
          int ng = n_base + n;
          int bi = ng >> lgHW;
          int yx = ng & ((1 << lgHW) - 1);
          ((unsigned short*)outp)[(((size_t)bi * Cout + m) << lgHW) + yx] = f2bf(c);
        } else if (EPI == 1) {
          ((unsigned short*)outp)[(size_t)m * N + n] = f2bf(c + biasN[n]);
        } else {
          ((float*)outp)[(size_t)m * ldOut + n_base + n] = c + biasN[n_base + n];
        }
      }
    }
  }
}

// ---------- fused 20-step recurrence: attention + LSTM, one persistent kernel ----------
// grid = 64 blocks x 256 threads (co-resident: 64 <= 256 CUs). 2 grid barriers / step.
// Attention phase: block b = batch b (all 64 blocks). LSTM phase: blocks 0..31 (16 units each).
__global__ __launch_bounds__(256)
void rec_k(const unsigned short* __restrict__ w_ih, const unsigned short* __restrict__ w_hh,
           const float* __restrict__ b_ih, const float* __restrict__ b_hh,
           const unsigned short* __restrict__ vproj, const unsigned short* __restrict__ visE,
           const float* __restrict__ att_wt, const float* __restrict__ att_bt,
           const float* __restrict__ att_wa, const float* __restrict__ att_ba,
           const int* __restrict__ captions, const float* __restrict__ emb,
           unsigned short* __restrict__ xin, unsigned short* __restrict__ h0,
           unsigned short* __restrict__ h1, float* __restrict__ cT,
           unsigned short* __restrict__ hs, unsigned int* __restrict__ bar)
{
  __shared__ __align__(16) float sH[512];
  __shared__ float sT[512];
  __shared__ float sSc[16];
  __shared__ float sAw[16];
  __shared__ float sG[4][16][64];  // [gate][unit-in-block][batch]
  const int tid = threadIdx.x;
  const int bid = blockIdx.x;

  for (int t = 0; t < 20; ++t) {
    const unsigned short* hin = (t & 1) ? h1 : h0;
    unsigned short* hout = (t & 1) ? h0 : h1;

    // ================= attention phase (block = batch) =================
    {
      const int b = bid;
      for (int i = tid; i < 512; i += 256) sH[i] = bf2f(hin[b * 512 + i]);
      __syncthreads();

      // tvec = att_wt @ h + att_bt  (f32 weights, L2-resident after step 0)
      for (int j = tid; j < 512; j += 256) {
        const float* wr = att_wt + (size_t)j * 512;
        float acc = 0.0f;
        #pragma unroll 4
        for (int k = 0; k < 512; k += 4) {
          float4 wv = *reinterpret_cast<const float4*>(wr + k);
          acc += wv.x * sH[k] + wv.y * sH[k + 1] + wv.z * sH[k + 2] + wv.w * sH[k + 3];
        }
        sT[j] = acc + att_bt[j];
      }
      __syncthreads();

      // scores: 16 threads per region, 32 k each
      {
        int r = tid >> 4, l16 = tid & 15;
        const unsigned short* vp = vproj + ((size_t)b * 16 + r) * 512;
        float s = 0.0f;
        int k0 = l16 * 32;
        for (int k = k0; k < k0 + 32; k++)
          s += tanhf(bf2f(vp[k]) + sT[k]) * att_wa[k];
        for (int d = 8; d >= 1; d >>= 1) s += __shfl_down(s, d, 16);
        if (l16 == 0) sSc[r] = s + att_ba[0];
      }
      __syncthreads();

      if (tid < 16) {
        float s = sSc[tid];
        float m = s;
        for (int d = 8; d >= 1; d >>= 1) m = fmaxf(m, __shfl_xor(m, d, 16));
        float e = expf(s - m);
        float sum = e;
        for (int d = 8; d >= 1; d >>= 1) sum += __shfl_xor(sum, d, 16);
        sAw[tid] = e / sum;
      }
      __syncthreads();

      {
        int e = tid; // 0..255
        float a = 0.0f;
        #pragma unroll
        for (int r = 0; r < 16; r++)
          a += sAw[r] * bf2f(visE[((size_t)b * 16 + r) * 256 + e]);
        int cap = captions[b * 20 + t];
        xin[b * 512 + e] = f2bf(emb[(size_t)cap * 256 + e]);  // word embedding (f32 src)
        xin[b * 512 + 256 + e] = f2bf(a);                     // attended
      }
    }
    gbar(bar, 64);   // xin ready

    // ================= LSTM phase (blocks 0..31) =================
    if (bid < 32) {
      const int u0  = bid * 16;
      const int w   = tid >> 6;
      const int l   = tid & 63;
      const int l15 = l & 15;
      const int q   = l >> 4;
      const int arow = w * 512 + u0 + l15;                  // 0..2047
      const unsigned short* Ai = w_ih + (size_t)arow * 512 + q * 8;
      const unsigned short* Ah = w_hh + (size_t)arow * 512 + q * 8;
      const unsigned short* Bx = xin  + (size_t)l15 * 512 + q * 8;
      const unsigned short* Bh = hin  + (size_t)l15 * 512 + q * 8;

      floatx4 acc[4];
      #pragma unroll
      for (int nt = 0; nt < 4; nt++) acc[nt] = (floatx4){0.f, 0.f, 0.f, 0.f};

      for (int kc = 0; kc < 512; kc += 32) {
        short8 a = ld8(Ai + kc);
        #pragma unroll
        for (int nt = 0; nt < 4; nt++) {
          short8 bf = ld8(Bx + (size_t)(nt * 16) * 512 + kc);
          acc[nt] = __builtin_amdgcn_mfma_f32_16x16x32_bf16(a, bf, acc[nt], 0, 0, 0);
        }
        a = ld8(Ah + kc);
        #pragma unroll
        for (int nt = 0; nt < 4; nt++) {
          short8 bf = ld8(Bh + (size_t)(nt * 16) * 512 + kc);
          acc[nt] = __builtin_amdgcn_mfma_f32_16x16x32_bf16(a, bf, acc[nt], 0, 0, 0);
        }
      }
      #pragma unroll
      for (int nt = 0; nt < 4; nt++)
        #pragma unroll
        for (int r = 0; r < 4; r++)
          sG[w][q * 4 + r][nt * 16 + l15] = acc[nt][r];
      __syncthreads();

      const int batch = tid & 63;
      const int g0 = tid >> 6;
      #pragma unroll
      for (int s = 0; s < 4; s++) {
        int um = g0 * 4 + s;     // 0..15
        int u = u0 + um;
        float ii = sG[0][um][batch] + b_ih[u]        + b_hh[u];
        float ff = sG[1][um][batch] + b_ih[512 + u]  + b_hh[512 + u];
        float gg = sG[2][um][batch] + b_ih[1024 + u] + b_hh[1024 + u];
        float oo = sG[3][um][batch] + b_ih[1536 + u] + b_hh[1536 + u];
        float co = cT[u * 64 + batch];
        float cn = sigmoidf_(ff) * co + sigmoidf_(ii) * tanhf(gg);
        float hn = sigmoidf_(oo) * tanhf(cn);
        cT[u * 64 + batch] = cn;
        unsigned short hb = f2bf(hn);
        hout[(size_t)batch * 512 + u] = hb;
        hs[((size_t)batch * 20 + t) * 512 + u] = hb;
      }
    }
    gbar(bar, 64);   // h_t ready
  }
}

// ---------- launch ----------
extern "C" void kernel_launch(void* const* d_in, const int* in_sizes, int n_in,
                              void* d_out, int out_size, void* d_ws, size_t ws_size,
                              hipStream_t stream)
{
  const float* images   = (const float*)d_in[0];
  const int*   captions = (const int*)d_in[1];
  const float* cw[4] = {(const float*)d_in[2],  (const float*)d_in[8],
                        (const float*)d_in[14], (const float*)d_in[20]};
  const float* cbp[4] = {(const float*)d_in[3],  (const float*)d_in[9],
                         (const float*)d_in[15], (const float*)d_in[21]};
  const float* bgp[4] = {(const float*)d_in[4],  (const float*)d_in[10],
                         (const float*)d_in[16], (const float*)d_in[22]};
  const float* bbp[4] = {(const float*)d_in[5],  (const float*)d_in[11],
                         (const float*)d_in[17], (const float*)d_in[23]};
  const float* bmp[4] = {(const float*)d_in[6],  (const float*)d_in[12],
                         (const float*)d_in[18], (const float*)d_in[24]};
  const float* bvp[4] = {(const float*)d_in[7],  (const float*)d_in[13],
                         (const float*)d_in[19], (const float*)d_in[25]};
  const float* proj_w = (const float*)d_in[26];
  const float* proj_b = (const float*)d_in[27];
  const float* emb    = (const float*)d_in[28];
  const float* att_wv = (const float*)d_in[29];
  const float* att_bv = (const float*)d_in[30];
  const float* att_wt = (const float*)d_in[31];
  const float* att_bt = (const float*)d_in[32];
  const float* att_wa = (const float*)d_in[33];
  const float* att_ba = (const float*)d_in[34];
  const float* w_ih   = (const float*)d_in[35];
  const float* w_hh   = (const float*)d_in[36];
  const float* b_ih   = (const float*)d_in[37];
  const float* b_hh   = (const float*)d_in[38];
  const float* out_w  = (const float*)d_in[39];
  const float* out_b  = (const float*)d_in[40];

  char* W = (char*)d_ws;
  unsigned short* wih_b = (unsigned short*)(W + OFF_WIH);
  unsigned short* whh_b = (unsigned short*)(W + OFF_WHH);
  unsigned short* vproj = (unsigned short*)(W + OFF_VPROJ);
  unsigned short* visE  = (unsigned short*)(W + OFF_VISE);
  unsigned short* hs    = (unsigned short*)(W + OFF_HS);
  unsigned short* xin   = (unsigned short*)(W + OFF_XIN);
  unsigned short* h0    = (unsigned short*)(W + OFF_H0);
  unsigned short* h1    = (unsigned short*)(W + OFF_H1);
  float*          cT    = (float*)(W + OFF_CT);
  unsigned short* w1pad = (unsigned short*)(W + OFF_W1PAD);
  unsigned short* cw2_b = (unsigned short*)(W + OFF_CW2);
  unsigned short* cw3_b = (unsigned short*)(W + OFF_CW3);
  unsigned short* cw4_b = (unsigned short*)(W + OFF_CW4);
  unsigned short* prw_b = (unsigned short*)(W + OFF_PRJW);
  unsigned short* awv_b = (unsigned short*)(W + OFF_ATWV);
  unsigned short* act1  = (unsigned short*)(W + OFF_ACT1);
  unsigned short* act2  = (unsigned short*)(W + OFF_ACT2);
  unsigned short* act3  = (unsigned short*)(W + OFF_ACT3);
  unsigned short* act4  = (unsigned short*)(W + OFF_ACT4);
  unsigned short* visA  = (unsigned short*)(W + OFF_VISA);
  unsigned short* col   = (unsigned short*)(W + OFF_COL);
  unsigned int*   bar   = (unsigned int*)(W + OFF_BAR);
  const bool big = (ws_size >= NEED_BIG);
  unsigned short* colb  = big ? (unsigned short*)(W + OFF_BIG) : col;

  init_k<<<128, 256, 0, stream>>>(cw[0], w1pad, h0, cT, bar);

  // fused weight conversions f32 -> bf16 (one dispatch instead of 7)
  {
    CvtArgs ca;
    ca.s[0] = w_ih;   ca.d[0] = wih_b;
    ca.s[1] = w_hh;   ca.d[1] = whh_b;
    ca.s[2] = cw[1];  ca.d[2] = cw2_b;
    ca.s[3] = cw[2];  ca.d[3] = cw3_b;
    ca.s[4] = cw[3];  ca.d[4] = cw4_b;
    ca.s[5] = proj_w; ca.d[5] = prw_b;
    ca.s[6] = att_wv; ca.d[6] = awv_b;
    int c0 = 0;
    int cnt[7] = {262144, 262144, 18432, 73728, 294912, 32768, 32768};
    ca.cum[0] = 0;
    for (int i = 0; i < 7; i++) { c0 += cnt[i]; ca.cum[i + 1] = c0; }
    cvtall_k<<<(c0 + 255) / 256, 256, 0, stream>>>(ca);   // 3816 blocks
  }

  // conv1: (64,3,64,64) -> (64,64,32,32)
  im2col1_k<<<8192, 256, 0, stream>>>(images, col);
  gemm_k<0><<<dim3(256, 1), 256, 0, stream>>>(w1pad, col, 32, 65536, act1,
      cbp[0], bgp[0], bbp[0], bmp[0], bvp[0], 64, 10, nullptr, 0, 0);

  if (big) {
    // conv2: single chunk (col 18.9 MB in big arena), gemm 128 blocks
    im2col_k<<<16384, 256, 0, stream>>>(act1, colb, 64, 32, 32, 576, 576, 8, 4, 0);
    gemm_k<0><<<dim3(64, 2), 256, 0, stream>>>(cw2_b, colb, 576, 16384, act2,
        cbp[1], bgp[1], bbp[1], bmp[1], bvp[1], 128, 8, nullptr, 0, 0);
    // conv3: single chunk, gemm 64 blocks
    im2col_k<<<4096, 256, 0, stream>>>(act2, colb, 128, 16, 16, 1152, 1152, 6, 3, 0);
    gemm_k<0><<<dim3(16, 4), 256, 0, stream>>>(cw3_b, colb, 1152, 4096, act3,
        cbp[2], bgp[2], bbp[2], bmp[2], bvp[2], 256, 6, nullptr, 0, 0);
  } else {
    for (int c = 0; c < 4; c++) {
      im2col_k<<<4096, 256, 0, stream>>>(act1, col, 64, 32, 32, 576, 576, 8, 4, c * 4096);
      gemm_k<0><<<dim3(16, 2), 256, 0, stream>>>(cw2_b, col, 576, 4096, act2,
          cbp[1], bgp[1], bbp[1], bmp[1], bvp[1], 128, 8, nullptr, c * 4096, 0);
    }
    for (int c = 0; c < 2; c++) {
      im2col_k<<<2048, 256, 0, stream>>>(act2, col, 128, 16, 16, 1152, 1152, 6, 3, c * 2048);
      gemm_k<0><<<dim3(8, 4), 256, 0, stream>>>(cw3_b, col, 1152, 2048, act3,
          cbp[2], bgp[2], bbp[2], bmp[2], bvp[2], 256, 6, nullptr, c * 2048, 0);
    }
  }
  // conv4: -> (64,512,4,4); act4 overlays act2
  im2col_k<<<1024, 256, 0, stream>>>(act3, col, 256, 8, 8, 2304, 2304, 4, 2, 0);
  gemm_k<0><<<dim3(4, 8), 256, 0, stream>>>(cw4_b, col, 2304, 1024, act4,
      cbp[3], bgp[3], bbp[3], bmp[3], bvp[3], 512, 4, nullptr, 0, 0);

  // visual gather + projections
  visa_k<<<2048, 256, 0, stream>>>(act4, visA);
  gemm_k<1><<<dim3(1, 16), 256, 0, stream>>>(visA, prw_b, 512, 256, visE,
      nullptr, nullptr, nullptr, nullptr, nullptr, 0, 0, proj_b, 0, 0);
  gemm_k<1><<<dim3(2, 16), 256, 0, stream>>>(visE, awv_b, 256, 512, vproj,
      nullptr, nullptr, nullptr, nullptr, nullptr, 0, 0, att_bv, 0, 0);

  // fused 20-step recurrence: 1 dispatch instead of 40
  rec_k<<<64, 256, 0, stream>>>(wih_b, whh_b, b_ih, b_hh, vproj, visE,
                                att_wt, att_bt, att_wa, att_ba, captions, emb,
                                xin, h0, h1, cT, hs, bar);

  // logits: (1280,512) x (32000,512)^T -> d_out f32 (B,T,V)
  if (big) {
    unsigned short* owb = (unsigned short*)(W + OFF_BIG);
    cvt_k<<<16000, 256, 0, stream>>>(out_w, owb, 32000 * 512 / 4);
    gemm_k<2><<<dim3(125, 20), 256, 0, stream>>>(hs, owb, 512, 32000,
        d_out, nullptr, nullptr, nullptr, nullptr, nullptr, 0, 0, out_b, 0, 32000);
  } else {
    for (int c = 0; c < 8; c++) {
      int rows = (c < 7) ? 4096 : 3328;
      const float* src = out_w + (size_t)c * 4096 * 512;
      cvt_k<<<rows / 2, 256, 0, stream>>>(src, col, rows * 512 / 4);
      gemm_k<2><<<dim3(rows / 256, 20), 256, 0, stream>>>(hs, col, 512, rows,
          d_out, nullptr, nullptr, nullptr, nullptr, nullptr, 0, 0, out_b, c * 4096, 32000);
    }
  }
}

// Round 2
// 1884.204 us; speedup vs baseline: 1.2747x; 1.2747x over previous
//
#include <hip/hip_runtime.h>
#include <hip/hip_bf16.h>
#include <cstdint>
#include <cstddef>

// ---------- types / helpers ----------
typedef __attribute__((ext_vector_type(8))) short short8;   // 8 x bf16 (4 VGPRs)
typedef __attribute__((ext_vector_type(4))) float floatx4;  // mfma accumulator

__device__ inline float bf2f(unsigned short u) {
  union { unsigned int i; float f; } v; v.i = ((unsigned int)u) << 16; return v.f;
}
__device__ inline unsigned short f2bf(float f) {
  union { float f; unsigned int i; } v; v.f = f;
  unsigned int u = v.i;
  return (unsigned short)((u + 0x7FFFu + ((u >> 16) & 1u)) >> 16); // RNE
}
__device__ inline short8 ld8(const unsigned short* p) {
  return *reinterpret_cast<const short8*>(p); // 16B aligned everywhere we use it
}
__device__ inline float sigmoidf_(float x) { return 1.0f / (1.0f + expf(-x)); }

// relaxed agent-scope atomics: compile to sc0/sc1 cache-bypass loads/stores,
// coherent across XCDs with NO buffer_wbl2/buffer_inv fences.
#define AT_LD(p)    __hip_atomic_load((p), __ATOMIC_RELAXED, __HIP_MEMORY_SCOPE_AGENT)
#define AT_ST(p, v) __hip_atomic_store((p), (v), __ATOMIC_RELAXED, __HIP_MEMORY_SCOPE_AGENT)
#define WAITCNT0()  asm volatile("s_waitcnt vmcnt(0) lgkmcnt(0)" ::: "memory")

// ---------- workspace layout (bytes) ----------
static const size_t OFF_WIH   = 0;          // 2,097,152  bf16 w_ih (2048,512)
static const size_t OFF_WHH   = 2097152;    // 2,097,152  bf16 w_hh (2048,512)
static const size_t OFF_VPROJ = 4194304;    // 1,048,576  bf16 (1024,512)
static const size_t OFF_VISE  = 5242880;    //   524,288  bf16 (1024,256)
static const size_t OFF_HS    = 5767168;    // 1,310,720  bf16 (1280,512) row=b*20+t
static const size_t OFF_XIN   = 7077888;    //    65,536  bf16 (64,512)
static const size_t OFF_H0    = 7143424;    //    65,536  bf16 (64,512)
static const size_t OFF_H1    = 7208960;    //    65,536  bf16 (64,512)
static const size_t OFF_CT    = 7274496;    //   131,072  f32  (512,64)
static const size_t OFF_W1PAD = 7405568;    //     4,096  bf16 (64,32)
static const size_t OFF_CW2   = 7409664;    //   147,456  bf16 (128,576)
static const size_t OFF_CW3   = 7557120;    //   589,824  bf16 (256,1152)
static const size_t OFF_CW4   = 8146944;    // 2,359,296  bf16 (512,2304)
static const size_t OFF_PRJW  = 10506240;   //   262,144  bf16 (256,512)
static const size_t OFF_ATWV  = 10768384;   //   262,144  bf16 (512,256)
static const size_t OFF_ACT1  = 11030528;   // 8,388,608  bf16 (64,64,32,32); act3 reuses
static const size_t OFF_ACT3  = 11030528;   // 2,097,152  bf16 (64,256,8,8)
static const size_t OFF_ACT2  = 19419136;   // 4,194,304  bf16 (64,128,16,16); act4+visA reuse
static const size_t OFF_ACT4  = 19419136;   // 1,048,576  bf16 (64,512,4,4)
static const size_t OFF_VISA  = 20467712;   // 1,048,576  bf16 (1024,512)
static const size_t OFF_COL   = 23613440;   // 4,718,592  small im2col arena / out_w chunks
static const size_t OFF_BAR   = 28332032;   //    16,384  grid-barrier flags (4096 uints)
static const size_t OFF_ATWT  = 28348416;   //   524,288  bf16 att_wt (512,512)
static const size_t OFF_BIG   = 28872704;   // optional: 32,768,000 big arena
static const size_t NEED_BIG  = OFF_BIG + 32768000; // 61,640,704

// ---------- fence-free grid barrier: per-block flags + broadcast go ----------
// bar[bid*32] = arrival slot (distinct cachelines), bar[2048] = go. Generations monotonic.
__device__ inline void grid_bar(unsigned int* bar, unsigned int gen) {
  WAITCNT0();                 // each wave: own global stores complete (incl. sc-bypass)
  __syncthreads();            // whole block's stores complete
  if (threadIdx.x == 0)
    AT_ST(bar + (size_t)blockIdx.x * 32, gen);
  if (blockIdx.x == 0 && threadIdx.x < 64) {
    while (AT_LD(bar + (size_t)threadIdx.x * 32) < gen) __builtin_amdgcn_s_sleep(1);
    if (threadIdx.x == 0) AT_ST(bar + 2048, gen);
  }
  if (threadIdx.x == 0) {
    while (AT_LD(bar + 2048) < gen) __builtin_amdgcn_s_sleep(1);
  }
  __syncthreads();
  asm volatile("" ::: "memory");
}

// ---------- f32 -> bf16 bulk convert (4 elems/thread) ----------
__global__ void cvt_k(const float* __restrict__ s, unsigned short* __restrict__ d, int n4)
{
  int i = blockIdx.x * 256 + threadIdx.x;
  if (i < n4) {
    float4 v = reinterpret_cast<const float4*>(s)[i];
    ushort4 o;
    o.x = f2bf(v.x); o.y = f2bf(v.y); o.z = f2bf(v.z); o.w = f2bf(v.w);
    reinterpret_cast<ushort4*>(d)[i] = o;
  }
}

// ---------- fused multi-segment f32 -> bf16 convert (8 tensors, one dispatch) ----------
struct CvtArgs {
  const float* s[8];
  unsigned short* d[8];
  int cum[9];  // cumulative float4 counts, cum[0]=0
};
__global__ void cvtall_k(CvtArgs a)
{
  int i = blockIdx.x * 256 + threadIdx.x;
  if (i >= a.cum[8]) return;
  int seg = 0;
  while (seg < 7 && i >= a.cum[seg + 1]) ++seg;
  int j = i - a.cum[seg];
  float4 v = reinterpret_cast<const float4*>(a.s[seg])[j];
  ushort4 o;
  o.x = f2bf(v.x); o.y = f2bf(v.y); o.z = f2bf(v.z); o.w = f2bf(v.w);
  reinterpret_cast<ushort4*>(a.d[seg])[j] = o;
}

// ---------- init: conv1 weight K-pad (f32->bf16), zero h0 / c / barrier ----------
__global__ void init_k(const float* __restrict__ conv1_w, unsigned short* __restrict__ w1pad,
                       unsigned short* __restrict__ h0, float* __restrict__ cT,
                       unsigned int* __restrict__ bar)
{
  int i = blockIdx.x * 256 + threadIdx.x;               // grid covers 32768
  if (i < 64 * 32) {
    int co = i >> 5, k = i & 31;
    w1pad[i] = (k < 27) ? f2bf(conv1_w[co * 27 + k]) : (unsigned short)0;
  }
  if (i < 64 * 512) h0[i] = 0;
  if (i < 512 * 64) cT[i] = 0.0f;
  if (i < 4096) bar[i] = 0u;   // reset grid-barrier flags every replay
}

// ---------- conv1 im2col: one thread per (pixel,k) element ----------
__global__ void im2col1_k(const float* __restrict__ in, unsigned short* __restrict__ col)
{
  int o = blockIdx.x * 256 + threadIdx.x;   // 65536 pixels * 32 Kpad = 2,097,152
  int n = o >> 5, k = o & 31;
  unsigned short v = 0;
  if (k < 27) {
    int b = n >> 10, y = (n >> 5) & 31, x = n & 31;
    int ci = k / 9, r9 = k - ci * 9, ky = r9 / 3, kx = r9 - ky * 3;
    int iy = 2 * y - 1 + ky, ix = 2 * x - 1 + kx;
    if (iy >= 0 && iy < 64 && ix >= 0 && ix < 64)
      v = f2bf(in[(((size_t)b * 3 + ci) << 12) + (iy << 6) + ix]);
  }
  col[o] = v;
}

// ---------- im2col (chunked): col[local n][k] bf16; global n = n0 + blockIdx.x ----------
__global__ void im2col_k(const unsigned short* __restrict__ in, unsigned short* __restrict__ col,
                         int Cin, int Hin, int Win, int Kreal, int Kpad, int lgHW, int lgW,
                         int n0)
{
  const int ng = n0 + blockIdx.x;
  const int b = ng >> lgHW;
  const int yx = ng & ((1 << lgHW) - 1);
  const int y = yx >> lgW;
  const int x = yx & ((1 << lgW) - 1);
  const int iy0 = 2 * y - 1;
  const int ix0 = 2 * x - 1;
  for (int k = threadIdx.x; k < Kpad; k += blockDim.x) {
    unsigned short v = 0;
    if (k < Kreal) {
      int ci = k / 9;
      int r9 = k - ci * 9;
      int ky = r9 / 3;
      int kx = r9 - ky * 3;
      int iy = iy0 + ky, ix = ix0 + kx;
      if (iy >= 0 && iy < Hin && ix >= 0 && ix < Win) {
        size_t idx = (((size_t)b * Cin + ci) * Hin + iy) * Win + ix;
        v = in[idx];
      }
    }
    col[(size_t)blockIdx.x * Kpad + k] = v;
  }
}

// ---------- gather visual: visA[(b*16+r)*512+c] = act4[b][c][r] ----------
__global__ void visa_k(const unsigned short* __restrict__ act4, unsigned short* __restrict__ visA)
{
  int o = blockIdx.x * 256 + threadIdx.x;   // 524288 total
  int c = o & 511, br = o >> 9;
  int b = br >> 4, r = br & 15;
  visA[o] = act4[(((size_t)b * 512 + c) << 4) + r];
}

// ---------- generic MFMA GEMM: C(M,N) = A(M,K) * B(N,K)^T, A/B bf16 ----------
template<int EPI>
__global__ __launch_bounds__(256)
void gemm_k(const unsigned short* __restrict__ A, const unsigned short* __restrict__ B,
            int K, int N, void* __restrict__ outp,
            const float* __restrict__ cb, const float* __restrict__ bg,
            const float* __restrict__ bb, const float* __restrict__ bm,
            const float* __restrict__ bv, int Cout, int lgHW,
            const float* __restrict__ biasN, int n_base, int ldOut)
{
  const int w   = threadIdx.x >> 6;
  const int l   = threadIdx.x & 63;
  const int l15 = l & 15;
  const int q   = l >> 4;
  const int m0  = blockIdx.y * 64;
  const int n0  = blockIdx.x * 256 + w * 64;
  const unsigned short* Ap = A + (size_t)(m0 + l15) * K + q * 8;
  const unsigned short* Bp = B + (size_t)(n0 + l15) * K + q * 8;

  floatx4 acc[4][4];
  #pragma unroll
  for (int i = 0; i < 4; i++)
    #pragma unroll
    for (int j = 0; j < 4; j++)
      acc[i][j] = (floatx4){0.f, 0.f, 0.f, 0.f};

  for (int kc = 0; kc < K; kc += 32) {
    short8 a0 = ld8(Ap + kc);
    short8 a1 = ld8(Ap + (size_t)16 * K + kc);
    short8 a2 = ld8(Ap + (size_t)32 * K + kc);
    short8 a3 = ld8(Ap + (size_t)48 * K + kc);
    #pragma unroll
    for (int nf = 0; nf < 4; nf++) {
      short8 bf = ld8(Bp + (size_t)(nf * 16) * K + kc);
      acc[0][nf] = __builtin_amdgcn_mfma_f32_16x16x32_bf16(a0, bf, acc[0][nf], 0, 0, 0);
      acc[1][nf] = __builtin_amdgcn_mfma_f32_16x16x32_bf16(a1, bf, acc[1][nf], 0, 0, 0);
      acc[2][nf] = __builtin_amdgcn_mfma_f32_16x16x32_bf16(a2, bf, acc[2][nf], 0, 0, 0);
      acc[3][nf] = __builtin_amdgcn_mfma_f32_16x16x32_bf16(a3, bf, acc[3][nf], 0, 0, 0);
    }
  }
  // C/D layout (verified m89/m91): col = lane&15, row = (lane>>4)*4 + reg
  #pragma unroll
  for (int mf = 0; mf < 4; mf++) {
    #pragma unroll
    for (int r = 0; r < 4; r++) {
      int m = m0 + mf * 16 + q * 4 + r;
      float scale = 1.0f, shift = 0.0f;
      if (EPI == 0) {
        float inv = bg[m] / sqrtf(bv[m] + 1e-5f);
        scale = inv;
        shift = (cb[m] - bm[m]) * inv + bb[m];
      }
      #pragma unroll
      for (int nf = 0; nf < 4; nf++) {
        int n = n0 + nf * 16 + l15;
        float c = acc[mf][nf][r];
        if (EPI == 0) {
          c = fmaxf(c * scale + shift, 0.0f);
          int ng = n_base + n;
          int bi = ng >> lgHW;
          int yx = ng & ((1 << lgHW) - 1);
          ((unsigned short*)outp)[(((size_t)bi * Cout + m) << lgHW) + yx] = f2bf(c);
        } else if (EPI == 1) {
          ((unsigned short*)outp)[(size_t)m * N + n] = f2bf(c + biasN[n]);
        } else {
          ((float*)outp)[(size_t)m * ldOut + n_base + n] = c + biasN[n_base + n];
        }
      }
    }
  }
}

// ---------- fused 20-step recurrence, fence-free ----------
// grid = 64 blocks x 256 threads, all co-resident. All cross-block data (h, xin) moves
// via relaxed agent-scope atomic uints (sc-bypass, coherent). No threadfence anywhere.
// Attention: block b = batch b (64 blocks). LSTM: blocks 0..31, 16 units each;
// B-operands staged to LDS in 32KB K-halves with XOR swizzle (G4 fix).
__global__ __launch_bounds__(256)
void rec_k(const unsigned short* __restrict__ w_ih, const unsigned short* __restrict__ w_hh,
           const float* __restrict__ b_ih, const float* __restrict__ b_hh,
           const unsigned short* __restrict__ vproj, const unsigned short* __restrict__ visE,
           const unsigned short* __restrict__ atwt, const float* __restrict__ att_bt,
           const float* __restrict__ att_wa, const float* __restrict__ att_ba,
           const int* __restrict__ captions, const float* __restrict__ emb,
           unsigned int* xin_u, unsigned int* h0_u, unsigned int* h1_u,
           float* __restrict__ cT, unsigned short* __restrict__ hs,
           unsigned int* __restrict__ bar)
{
  __shared__ __align__(16) float sH[512];
  __shared__ float sT[512];
  __shared__ float sA[256];
  __shared__ float sSc[16];
  __shared__ float sAw[16];
  __shared__ __align__(16) unsigned short sB[16384];  // 32 KB staging (64 rows x 256 els)
  __shared__ float sG[4][16][64];

  const int tid = threadIdx.x;
  const int bid = blockIdx.x;
  const int w   = tid >> 6;
  const int l   = tid & 63;
  const int l15 = l & 15;
  const int q   = l >> 4;
  const int u0  = bid * 16;                 // LSTM unit base (blocks 0..31)
  const int arow = w * 512 + u0 + l15;      // gate-major weight row

  for (int t = 0; t < 20; ++t) {
    unsigned int* hin_u  = (t & 1) ? h1_u : h0_u;
    unsigned int* hout_u = (t & 1) ? h0_u : h1_u;

    // ================= attention (block = batch) =================
    {
      const int b = bid;
      unsigned int hv = AT_LD(hin_u + b * 256 + tid);
      sH[2 * tid]     = bf2f((unsigned short)(hv & 0xffffu));
      sH[2 * tid + 1] = bf2f((unsigned short)(hv >> 16));
      __syncthreads();

      // tvec = att_wt(bf16) @ h + att_bt : 2 rows per thread for ILP
      {
        const unsigned short* w0 = atwt + (size_t)tid * 512;
        const unsigned short* w1 = w0 + (size_t)256 * 512;
        float a0 = 0.f, a1 = 0.f;
        #pragma unroll 2
        for (int k = 0; k < 512; k += 8) {
          short8 x0 = ld8(w0 + k);
          short8 x1 = ld8(w1 + k);
          #pragma unroll
          for (int j = 0; j < 8; ++j) {
            float hk = sH[k + j];
            a0 += bf2f((unsigned short)x0[j]) * hk;
            a1 += bf2f((unsigned short)x1[j]) * hk;
          }
        }
        sT[tid]       = a0 + att_bt[tid];
        sT[tid + 256] = a1 + att_bt[tid + 256];
      }
      __syncthreads();

      // scores: 16 threads per region, 32 k each
      {
        int r = tid >> 4, l16 = tid & 15;
        const unsigned short* vp = vproj + ((size_t)b * 16 + r) * 512;
        float s = 0.0f;
        int k0 = l16 * 32;
        for (int k = k0; k < k0 + 32; k++)
          s += tanhf(bf2f(vp[k]) + sT[k]) * att_wa[k];
        for (int d = 8; d >= 1; d >>= 1) s += __shfl_down(s, d, 16);
        if (l16 == 0) sSc[r] = s + att_ba[0];
      }
      __syncthreads();

      if (tid < 16) {
        float s = sSc[tid];
        float m = s;
        for (int d = 8; d >= 1; d >>= 1) m = fmaxf(m, __shfl_xor(m, d, 16));
        float e = expf(s - m);
        float sum = e;
        for (int d = 8; d >= 1; d >>= 1) sum += __shfl_xor(sum, d, 16);
        sAw[tid] = e / sum;
      }
      __syncthreads();

      {
        float a = 0.0f;
        #pragma unroll
        for (int r = 0; r < 16; r++)
          a += sAw[r] * bf2f(visE[((size_t)b * 16 + r) * 256 + tid]);
        sA[tid] = a;
      }
      __syncthreads();

      // pack xin as uints: [0..127] word-embed half, [128..255] attended half
      if (tid < 128) {
        int cap = captions[b * 20 + t];
        float2 ev = *reinterpret_cast<const float2*>(emb + (size_t)cap * 256 + 2 * tid);
        AT_ST(xin_u + b * 256 + tid,
              (unsigned int)f2bf(ev.x) | ((unsigned int)f2bf(ev.y) << 16));
      } else {
        int j2 = 2 * (tid - 128);
        AT_ST(xin_u + b * 256 + tid,
              (unsigned int)f2bf(sA[j2]) | ((unsigned int)f2bf(sA[j2 + 1]) << 16));
      }
    }
    grid_bar(bar, 2 * t + 1);   // xin ready

    // ================= LSTM (blocks 0..31) =================
    if (bid < 32) {
      floatx4 acc[4];
      #pragma unroll
      for (int nt = 0; nt < 4; nt++) acc[nt] = (floatx4){0.f, 0.f, 0.f, 0.f};

      #pragma unroll
      for (int src = 0; src < 2; ++src) {
        unsigned int* Bu = src ? hin_u : xin_u;
        const unsigned short* Arow = (src ? w_hh : w_ih) + (size_t)arow * 512;
        #pragma unroll
        for (int half = 0; half < 2; ++half) {
          __syncthreads();   // previous sB use finished
          // stage 8192 uints (64 batches x 128 uints) via bypass loads, swizzled
          for (int i = tid; i < 8192; i += 256) {
            int row = i >> 7, cu = i & 127;
            unsigned int v = AT_LD(Bu + row * 256 + half * 128 + cu);
            reinterpret_cast<unsigned int*>(sB)[(row * 128 + cu) ^ ((row & 7) << 2)] = v;
          }
          __syncthreads();
          const unsigned short* Ap = Arow + half * 256 + q * 8;
          #pragma unroll
          for (int kc = 0; kc < 256; kc += 32) {
            short8 a = ld8(Ap + kc);
            #pragma unroll
            for (int nt = 0; nt < 4; ++nt) {
              int row = l15 + nt * 16;
              short8 bf = *reinterpret_cast<const short8*>(
                  sB + (((size_t)row * 256 + q * 8 + kc) ^ ((row & 7) << 3)));
              acc[nt] = __builtin_amdgcn_mfma_f32_16x16x32_bf16(a, bf, acc[nt], 0, 0, 0);
            }
          }
        }
      }
      #pragma unroll
      for (int nt = 0; nt < 4; nt++)
        #pragma unroll
        for (int r = 0; r < 4; r++)
          sG[w][q * 4 + r][nt * 16 + l15] = acc[nt][r];
      __syncthreads();

      const int batch = tid & 63;
      const int g0 = tid >> 6;
      #pragma unroll
      for (int s = 0; s < 4; s += 2) {
        float hn2[2];
        #pragma unroll
        for (int d = 0; d < 2; ++d) {
          int um = g0 * 4 + s + d;
          int u = u0 + um;
          float ii = sG[0][um][batch] + b_ih[u]        + b_hh[u];
          float ff = sG[1][um][batch] + b_ih[512 + u]  + b_hh[512 + u];
          float gg = sG[2][um][batch] + b_ih[1024 + u] + b_hh[1024 + u];
          float oo = sG[3][um][batch] + b_ih[1536 + u] + b_hh[1536 + u];
          float co = cT[u * 64 + batch];
          float cn = sigmoidf_(ff) * co + sigmoidf_(ii) * tanhf(gg);
          hn2[d] = sigmoidf_(oo) * tanhf(cn);
          cT[u * 64 + batch] = cn;
        }
        int u = u0 + g0 * 4 + s;
        unsigned int hp = (unsigned int)f2bf(hn2[0]) | ((unsigned int)f2bf(hn2[1]) << 16);
        AT_ST(hout_u + batch * 256 + (u >> 1), hp);
        *reinterpret_cast<unsigned int*>(hs + ((size_t)batch * 20 + t) * 512 + u) = hp;
      }
    }
    grid_bar(bar, 2 * t + 2);   // h_t ready
  }
}

// ---------- launch ----------
extern "C" void kernel_launch(void* const* d_in, const int* in_sizes, int n_in,
                              void* d_out, int out_size, void* d_ws, size_t ws_size,
                              hipStream_t stream)
{
  const float* images   = (const float*)d_in[0];
  const int*   captions = (const int*)d_in[1];
  const float* cw[4] = {(const float*)d_in[2],  (const float*)d_in[8],
                        (const float*)d_in[14], (const float*)d_in[20]};
  const float* cbp[4] = {(const float*)d_in[3],  (const float*)d_in[9],
                         (const float*)d_in[15], (const float*)d_in[21]};
  const float* bgp[4] = {(const float*)d_in[4],  (const float*)d_in[10],
                         (const float*)d_in[16], (const float*)d_in[22]};
  const float* bbp[4] = {(const float*)d_in[5],  (const float*)d_in[11],
                         (const float*)d_in[17], (const float*)d_in[23]};
  const float* bmp[4] = {(const float*)d_in[6],  (const float*)d_in[12],
                         (const float*)d_in[18], (const float*)d_in[24]};
  const float* bvp[4] = {(const float*)d_in[7],  (const float*)d_in[13],
                         (const float*)d_in[19], (const float*)d_in[25]};
  const float* proj_w = (const float*)d_in[26];
  const float* proj_b = (const float*)d_in[27];
  const float* emb    = (const float*)d_in[28];
  const float* att_wv = (const float*)d_in[29];
  const float* att_bv = (const float*)d_in[30];
  const float* att_wt = (const float*)d_in[31];
  const float* att_bt = (const float*)d_in[32];
  const float* att_wa = (const float*)d_in[33];
  const float* att_ba = (const float*)d_in[34];
  const float* w_ih   = (const float*)d_in[35];
  const float* w_hh   = (const float*)d_in[36];
  const float* b_ih   = (const float*)d_in[37];
  const float* b_hh   = (const float*)d_in[38];
  const float* out_w  = (const float*)d_in[39];
  const float* out_b  = (const float*)d_in[40];

  char* W = (char*)d_ws;
  unsigned short* wih_b = (unsigned short*)(W + OFF_WIH);
  unsigned short* whh_b = (unsigned short*)(W + OFF_WHH);
  unsigned short* vproj = (unsigned short*)(W + OFF_VPROJ);
  unsigned short* visE  = (unsigned short*)(W + OFF_VISE);
  unsigned short* hs    = (unsigned short*)(W + OFF_HS);
  unsigned short* xin   = (unsigned short*)(W + OFF_XIN);
  unsigned short* h0    = (unsigned short*)(W + OFF_H0);
  unsigned short* h1    = (unsigned short*)(W + OFF_H1);
  float*          cT    = (float*)(W + OFF_CT);
  unsigned short* w1pad = (unsigned short*)(W + OFF_W1PAD);
  unsigned short* cw2_b = (unsigned short*)(W + OFF_CW2);
  unsigned short* cw3_b = (unsigned short*)(W + OFF_CW3);
  unsigned short* cw4_b = (unsigned short*)(W + OFF_CW4);
  unsigned short* prw_b = (unsigned short*)(W + OFF_PRJW);
  unsigned short* awv_b = (unsigned short*)(W + OFF_ATWV);
  unsigned short* atwt_b= (unsigned short*)(W + OFF_ATWT);
  unsigned short* act1  = (unsigned short*)(W + OFF_ACT1);
  unsigned short* act2  = (unsigned short*)(W + OFF_ACT2);
  unsigned short* act3  = (unsigned short*)(W + OFF_ACT3);
  unsigned short* act4  = (unsigned short*)(W + OFF_ACT4);
  unsigned short* visA  = (unsigned short*)(W + OFF_VISA);
  unsigned short* col   = (unsigned short*)(W + OFF_COL);
  unsigned int*   bar   = (unsigned int*)(W + OFF_BAR);
  const bool big = (ws_size >= NEED_BIG);
  unsigned short* colb  = big ? (unsigned short*)(W + OFF_BIG) : col;

  init_k<<<128, 256, 0, stream>>>(cw[0], w1pad, h0, cT, bar);

  // fused weight conversions f32 -> bf16 (one dispatch instead of 8)
  {
    CvtArgs ca;
    ca.s[0] = w_ih;   ca.d[0] = wih_b;
    ca.s[1] = w_hh;   ca.d[1] = whh_b;
    ca.s[2] = cw[1];  ca.d[2] = cw2_b;
    ca.s[3] = cw[2];  ca.d[3] = cw3_b;
    ca.s[4] = cw[3];  ca.d[4] = cw4_b;
    ca.s[5] = proj_w; ca.d[5] = prw_b;
    ca.s[6] = att_wv; ca.d[6] = awv_b;
    ca.s[7] = att_wt; ca.d[7] = atwt_b;
    int c0 = 0;
    int cnt[8] = {262144, 262144, 18432, 73728, 294912, 32768, 32768, 65536};
    ca.cum[0] = 0;
    for (int i = 0; i < 8; i++) { c0 += cnt[i]; ca.cum[i + 1] = c0; }
    cvtall_k<<<(c0 + 255) / 256, 256, 0, stream>>>(ca);
  }

  // conv1: (64,3,64,64) -> (64,64,32,32)
  im2col1_k<<<8192, 256, 0, stream>>>(images, col);
  gemm_k<0><<<dim3(256, 1), 256, 0, stream>>>(w1pad, col, 32, 65536, act1,
      cbp[0], bgp[0], bbp[0], bmp[0], bvp[0], 64, 10, nullptr, 0, 0);

  if (big) {
    im2col_k<<<16384, 256, 0, stream>>>(act1, colb, 64, 32, 32, 576, 576, 8, 4, 0);
    gemm_k<0><<<dim3(64, 2), 256, 0, stream>>>(cw2_b, colb, 576, 16384, act2,
        cbp[1], bgp[1], bbp[1], bmp[1], bvp[1], 128, 8, nullptr, 0, 0);
    im2col_k<<<4096, 256, 0, stream>>>(act2, colb, 128, 16, 16, 1152, 1152, 6, 3, 0);
    gemm_k<0><<<dim3(16, 4), 256, 0, stream>>>(cw3_b, colb, 1152, 4096, act3,
        cbp[2], bgp[2], bbp[2], bmp[2], bvp[2], 256, 6, nullptr, 0, 0);
  } else {
    for (int c = 0; c < 4; c++) {
      im2col_k<<<4096, 256, 0, stream>>>(act1, col, 64, 32, 32, 576, 576, 8, 4, c * 4096);
      gemm_k<0><<<dim3(16, 2), 256, 0, stream>>>(cw2_b, col, 576, 4096, act2,
          cbp[1], bgp[1], bbp[1], bmp[1], bvp[1], 128, 8, nullptr, c * 4096, 0);
    }
    for (int c = 0; c < 2; c++) {
      im2col_k<<<2048, 256, 0, stream>>>(act2, col, 128, 16, 16, 1152, 1152, 6, 3, c * 2048);
      gemm_k<0><<<dim3(8, 4), 256, 0, stream>>>(cw3_b, col, 1152, 2048, act3,
          cbp[2], bgp[2], bbp[2], bmp[2], bvp[2], 256, 6, nullptr, c * 2048, 0);
    }
  }
  // conv4: -> (64,512,4,4); act4 overlays act2
  im2col_k<<<1024, 256, 0, stream>>>(act3, col, 256, 8, 8, 2304, 2304, 4, 2, 0);
  gemm_k<0><<<dim3(4, 8), 256, 0, stream>>>(cw4_b, col, 2304, 1024, act4,
      cbp[3], bgp[3], bbp[3], bmp[3], bvp[3], 512, 4, nullptr, 0, 0);

  // visual gather + projections
  visa_k<<<2048, 256, 0, stream>>>(act4, visA);
  gemm_k<1><<<dim3(1, 16), 256, 0, stream>>>(visA, prw_b, 512, 256, visE,
      nullptr, nullptr, nullptr, nullptr, nullptr, 0, 0, proj_b, 0, 0);
  gemm_k<1><<<dim3(2, 16), 256, 0, stream>>>(visE, awv_b, 256, 512, vproj,
      nullptr, nullptr, nullptr, nullptr, nullptr, 0, 0, att_bv, 0, 0);

  // fused 20-step recurrence: 1 dispatch, fence-free barriers
  rec_k<<<64, 256, 0, stream>>>(wih_b, whh_b, b_ih, b_hh, vproj, visE,
                                atwt_b, att_bt, att_wa, att_ba, captions, emb,
                                (unsigned int*)xin, (unsigned int*)h0, (unsigned int*)h1,
                                cT, hs, bar);

  // logits: (1280,512) x (32000,512)^T -> d_out f32 (B,T,V)
  if (big) {
    unsigned short* owb = (unsigned short*)(W + OFF_BIG);
    cvt_k<<<16000, 256, 0, stream>>>(out_w, owb, 32000 * 512 / 4);
    gemm_k<2><<<dim3(125, 20), 256, 0, stream>>>(hs, owb, 512, 32000,
        d_out, nullptr, nullptr, nullptr, nullptr, nullptr, 0, 0, out_b, 0, 32000);
  } else {
    for (int c = 0; c < 8; c++) {
      int rows = (c < 7) ? 4096 : 3328;
      const float* src = out_w + (size_t)c * 4096 * 512;
      cvt_k<<<rows / 2, 256, 0, stream>>>(src, col, rows * 512 / 4);
      gemm_k<2><<<dim3(rows / 256, 20), 256, 0, stream>>>(hs, col, 512, rows,
          d_out, nullptr, nullptr, nullptr, nullptr, nullptr, 0, 0, out_b, c * 4096, 32000);
    }
  }
}

// Round 3
// 1686.687 us; speedup vs baseline: 1.4240x; 1.1171x over previous
//
#include <hip/hip_runtime.h>
#include <hip/hip_bf16.h>
#include <cstdint>
#include <cstddef>

// ---------- types / helpers ----------
typedef __attribute__((ext_vector_type(8))) short short8;   // 8 x bf16 (4 VGPRs)
typedef __attribute__((ext_vector_type(4))) float floatx4;  // mfma accumulator

__device__ inline float bf2f(unsigned short u) {
  union { unsigned int i; float f; } v; v.i = ((unsigned int)u) << 16; return v.f;
}
__device__ inline unsigned short f2bf(float f) {
  union { float f; unsigned int i; } v; v.f = f;
  unsigned int u = v.i;
  return (unsigned short)((u + 0x7FFFu + ((u >> 16) & 1u)) >> 16); // RNE
}
__device__ inline short8 ld8(const unsigned short* p) {
  return *reinterpret_cast<const short8*>(p); // 16B aligned everywhere we use it
}
__device__ inline float sigmoidf_(float x) { return 1.0f / (1.0f + __expf(-x)); }
__device__ inline float tanh_fast(float x) {
  float e = __expf(2.0f * x);
  return 1.0f - 2.0f / (e + 1.0f);   // exact at saturation: +inf->1, 0->-1
}

// relaxed agent-scope atomics: sc-bypass loads/stores, coherent across XCDs, no L2 flush
#define AT_LD(p)    __hip_atomic_load((p), __ATOMIC_RELAXED, __HIP_MEMORY_SCOPE_AGENT)
#define AT_ST(p, v) __hip_atomic_store((p), (v), __ATOMIC_RELAXED, __HIP_MEMORY_SCOPE_AGENT)
#define WAITCNT0()  asm volatile("s_waitcnt vmcnt(0) lgkmcnt(0)" ::: "memory")
#define CFENCE()    asm volatile("" ::: "memory")

// ---------- workspace layout (bytes) ----------
static const size_t OFF_WIH   = 0;          // 2,097,152  bf16 w_ih (2048,512)
static const size_t OFF_WHH   = 2097152;    // 2,097,152  bf16 w_hh (2048,512)
static const size_t OFF_VPROJ = 4194304;    // 1,048,576  bf16 (1024,512)
static const size_t OFF_VISE  = 5242880;    //   524,288  bf16 (1024,256)
static const size_t OFF_HS    = 5767168;    // 1,310,720  bf16 (1280,512) row=b*20+t
static const size_t OFF_XIN   = 7077888;    //    65,536  bf16 attended (64,256) as uints
static const size_t OFF_H0    = 7143424;    //    65,536  bf16 (64,512)
static const size_t OFF_H1    = 7208960;    //    65,536  bf16 (64,512)
static const size_t OFF_CT    = 7274496;    //   131,072  (unused, kept for layout)
static const size_t OFF_W1PAD = 7405568;    //     4,096  bf16 (64,32)
static const size_t OFF_CW2   = 7409664;    //   147,456  bf16 (128,576)
static const size_t OFF_CW3   = 7557120;    //   589,824  bf16 (256,1152)
static const size_t OFF_CW4   = 8146944;    // 2,359,296  bf16 (512,2304)
static const size_t OFF_PRJW  = 10506240;   //   262,144  bf16 (256,512)
static const size_t OFF_ATWV  = 10768384;   //   262,144  bf16 (512,256)
static const size_t OFF_ACT1  = 11030528;   // 8,388,608  bf16 (64,64,32,32); act3 reuses
static const size_t OFF_ACT3  = 11030528;   // 2,097,152  bf16 (64,256,8,8)
static const size_t OFF_ACT2  = 19419136;   // 4,194,304  bf16 (64,128,16,16); act4+visA reuse
static const size_t OFF_ACT4  = 19419136;   // 1,048,576  bf16 (64,512,4,4)
static const size_t OFF_VISA  = 20467712;   // 1,048,576  bf16 (1024,512)
static const size_t OFF_COL   = 23613440;   // 4,718,592  small im2col arena / out_w chunks
static const size_t OFF_BAR   = 28332032;   //    16,384  flags: xf[64] @0, hf[32] @64
static const size_t OFF_ATWT  = 28348416;   //   524,288  bf16 att_wt (512,512)
static const size_t OFF_BIG   = 28872704;   // optional: 32,768,000 big arena
static const size_t NEED_BIG  = OFF_BIG + 32768000; // 61,640,704

// ---------- f32 -> bf16 bulk convert (4 elems/thread) ----------
__global__ void cvt_k(const float* __restrict__ s, unsigned short* __restrict__ d, int n4)
{
  int i = blockIdx.x * 256 + threadIdx.x;
  if (i < n4) {
    float4 v = reinterpret_cast<const float4*>(s)[i];
    ushort4 o;
    o.x = f2bf(v.x); o.y = f2bf(v.y); o.z = f2bf(v.z); o.w = f2bf(v.w);
    reinterpret_cast<ushort4*>(d)[i] = o;
  }
}

// ---------- fused multi-segment f32 -> bf16 convert (8 tensors, one dispatch) ----------
struct CvtArgs {
  const float* s[8];
  unsigned short* d[8];
  int cum[9];  // cumulative float4 counts, cum[0]=0
};
__global__ void cvtall_k(CvtArgs a)
{
  int i = blockIdx.x * 256 + threadIdx.x;
  if (i >= a.cum[8]) return;
  int seg = 0;
  while (seg < 7 && i >= a.cum[seg + 1]) ++seg;
  int j = i - a.cum[seg];
  float4 v = reinterpret_cast<const float4*>(a.s[seg])[j];
  ushort4 o;
  o.x = f2bf(v.x); o.y = f2bf(v.y); o.z = f2bf(v.z); o.w = f2bf(v.w);
  reinterpret_cast<ushort4*>(a.d[seg])[j] = o;
}

// ---------- init: conv1 weight K-pad (f32->bf16), zero h0 / flags ----------
__global__ void init_k(const float* __restrict__ conv1_w, unsigned short* __restrict__ w1pad,
                       unsigned short* __restrict__ h0, unsigned int* __restrict__ bar)
{
  int i = blockIdx.x * 256 + threadIdx.x;               // grid covers 32768
  if (i < 64 * 32) {
    int co = i >> 5, k = i & 31;
    w1pad[i] = (k < 27) ? f2bf(conv1_w[co * 27 + k]) : (unsigned short)0;
  }
  if (i < 64 * 512) h0[i] = 0;
  if (i < 4096) bar[i] = 0u;   // reset flags every replay
}

// ---------- conv1 im2col ----------
__global__ void im2col1_k(const float* __restrict__ in, unsigned short* __restrict__ col)
{
  int o = blockIdx.x * 256 + threadIdx.x;   // 65536 pixels * 32 Kpad = 2,097,152
  int n = o >> 5, k = o & 31;
  unsigned short v = 0;
  if (k < 27) {
    int b = n >> 10, y = (n >> 5) & 31, x = n & 31;
    int ci = k / 9, r9 = k - ci * 9, ky = r9 / 3, kx = r9 - ky * 3;
    int iy = 2 * y - 1 + ky, ix = 2 * x - 1 + kx;
    if (iy >= 0 && iy < 64 && ix >= 0 && ix < 64)
      v = f2bf(in[(((size_t)b * 3 + ci) << 12) + (iy << 6) + ix]);
  }
  col[o] = v;
}

// ---------- im2col (chunked) ----------
__global__ void im2col_k(const unsigned short* __restrict__ in, unsigned short* __restrict__ col,
                         int Cin, int Hin, int Win, int Kreal, int Kpad, int lgHW, int lgW,
                         int n0)
{
  const int ng = n0 + blockIdx.x;
  const int b = ng >> lgHW;
  const int yx = ng & ((1 << lgHW) - 1);
  const int y = yx >> lgW;
  const int x = yx & ((1 << lgW) - 1);
  const int iy0 = 2 * y - 1;
  const int ix0 = 2 * x - 1;
  for (int k = threadIdx.x; k < Kpad; k += blockDim.x) {
    unsigned short v = 0;
    if (k < Kreal) {
      int ci = k / 9;
      int r9 = k - ci * 9;
      int ky = r9 / 3;
      int kx = r9 - ky * 3;
      int iy = iy0 + ky, ix = ix0 + kx;
      if (iy >= 0 && iy < Hin && ix >= 0 && ix < Win) {
        size_t idx = (((size_t)b * Cin + ci) * Hin + iy) * Win + ix;
        v = in[idx];
      }
    }
    col[(size_t)blockIdx.x * Kpad + k] = v;
  }
}

// ---------- gather visual: visA[(b*16+r)*512+c] = act4[b][c][r] ----------
__global__ void visa_k(const unsigned short* __restrict__ act4, unsigned short* __restrict__ visA)
{
  int o = blockIdx.x * 256 + threadIdx.x;   // 524288 total
  int c = o & 511, br = o >> 9;
  int b = br >> 4, r = br & 15;
  visA[o] = act4[(((size_t)b * 512 + c) << 4) + r];
}

// ---------- generic MFMA GEMM: C(M,N) = A(M,K) * B(N,K)^T, A/B bf16 ----------
template<int EPI>
__global__ __launch_bounds__(256)
void gemm_k(const unsigned short* __restrict__ A, const unsigned short* __restrict__ B,
            int K, int N, void* __restrict__ outp,
            const float* __restrict__ cb, const float* __restrict__ bg,
            const float* __restrict__ bb, const float* __restrict__ bm,
            const float* __restrict__ bv, int Cout, int lgHW,
            const float* __restrict__ biasN, int n_base, int ldOut)
{
  const int w   = threadIdx.x >> 6;
  const int l   = threadIdx.x & 63;
  const int l15 = l & 15;
  const int q   = l >> 4;
  const int m0  = blockIdx.y * 64;
  const int n0  = blockIdx.x * 256 + w * 64;
  const unsigned short* Ap = A + (size_t)(m0 + l15) * K + q * 8;
  const unsigned short* Bp = B + (size_t)(n0 + l15) * K + q * 8;

  floatx4 acc[4][4];
  #pragma unroll
  for (int i = 0; i < 4; i++)
    #pragma unroll
    for (int j = 0; j < 4; j++)
      acc[i][j] = (floatx4){0.f, 0.f, 0.f, 0.f};

  for (int kc = 0; kc < K; kc += 32) {
    short8 a0 = ld8(Ap + kc);
    short8 a1 = ld8(Ap + (size_t)16 * K + kc);
    short8 a2 = ld8(Ap + (size_t)32 * K + kc);
    short8 a3 = ld8(Ap + (size_t)48 * K + kc);
    #pragma unroll
    for (int nf = 0; nf < 4; nf++) {
      short8 bf = ld8(Bp + (size_t)(nf * 16) * K + kc);
      acc[0][nf] = __builtin_amdgcn_mfma_f32_16x16x32_bf16(a0, bf, acc[0][nf], 0, 0, 0);
      acc[1][nf] = __builtin_amdgcn_mfma_f32_16x16x32_bf16(a1, bf, acc[1][nf], 0, 0, 0);
      acc[2][nf] = __builtin_amdgcn_mfma_f32_16x16x32_bf16(a2, bf, acc[2][nf], 0, 0, 0);
      acc[3][nf] = __builtin_amdgcn_mfma_f32_16x16x32_bf16(a3, bf, acc[3][nf], 0, 0, 0);
    }
  }
  // C/D layout (verified m89/m91): col = lane&15, row = (lane>>4)*4 + reg
  #pragma unroll
  for (int mf = 0; mf < 4; mf++) {
    #pragma unroll
    for (int r = 0; r < 4; r++) {
      int m = m0 + mf * 16 + q * 4 + r;
      float scale = 1.0f, shift = 0.0f;
      if (EPI == 0) {
        float inv = bg[m] / sqrtf(bv[m] + 1e-5f);
        scale = inv;
        shift = (cb[m] - bm[m]) * inv + bb[m];
      }
      #pragma unroll
      for (int nf = 0; nf < 4; nf++) {
        int n = n0 + nf * 16 + l15;
        float c = acc[mf][nf][r];
        if (EPI == 0) {
          c = fmaxf(c * scale + shift, 0.0f);
          int ng = n_base + n;
          int bi = ng >> lgHW;
          int yx = ng & ((1 << lgHW) - 1);
          ((unsigned short*)outp)[(((size_t)bi * Cout + m) << lgHW) + yx] = f2bf(c);
        } else if (EPI == 1) {
          ((unsigned short*)outp)[(size_t)m * N + n] = f2bf(c + biasN[n]);
        } else {
          ((float*)outp)[(size_t)m * ldOut + n_base + n] = c + biasN[n_base + n];
        }
      }
    }
  }
}

// ---------- fused 20-step recurrence, flat producer->consumer flags ----------
// grid = 64 blocks x 256 threads, co-resident. Flags packed (4 cachelines), bypass
// loads/stores for cross-XCD data. Embed half of xin loaded from read-only emb by
// LSTM blocks (cached); only attended half (32KB) crosses XCDs. c-state in registers.
__global__ __launch_bounds__(256)
void rec_k(const unsigned short* __restrict__ w_ih, const unsigned short* __restrict__ w_hh,
           const float* __restrict__ b_ih, const float* __restrict__ b_hh,
           const unsigned short* __restrict__ vproj, const unsigned short* __restrict__ visE,
           const unsigned short* __restrict__ atwt, const float* __restrict__ att_bt,
           const float* __restrict__ att_wa, const float* __restrict__ att_ba,
           const int* __restrict__ captions, const float* __restrict__ emb,
           unsigned int* xin_u, unsigned int* h0_u, unsigned int* h1_u,
           unsigned short* __restrict__ hs, unsigned int* __restrict__ bar)
{
  __shared__ __align__(16) float sH[512];
  __shared__ float sT[512];
  __shared__ float sA[256];
  __shared__ float sSc[16];
  __shared__ float sAw[16];
  __shared__ __align__(16) unsigned short sB[64 * 256];  // 32 KB B-tile, XOR-swizzled
  __shared__ float sG[4][16][64];

  unsigned int* xf = bar;        // 64 flags (attended ready), packed
  unsigned int* hf = bar + 64;   // 32 flags (h ready), packed

  const int tid = threadIdx.x;
  const int bid = blockIdx.x;
  const int w   = tid >> 6;
  const int l   = tid & 63;
  const int l15 = l & 15;
  const int q   = l >> 4;
  const int u0  = bid * 16;                 // LSTM unit base (blocks 0..31)
  const int arow = w * 512 + u0 + l15;      // gate-major weight row
  const unsigned short* wihRow = w_ih + (size_t)arow * 512;
  const unsigned short* whhRow = w_hh + (size_t)arow * 512;

  // persistent cell state + bias sums (LSTM blocks only)
  float creg[4];
  float bsum[4][4];   // [s][gate]
  if (bid < 32) {
    const int batch = tid & 63;
    const int g0 = tid >> 6;
    (void)batch;
    #pragma unroll
    for (int s = 0; s < 4; ++s) {
      creg[s] = 0.0f;
      int u = u0 + g0 * 4 + s;
      #pragma unroll
      for (int g = 0; g < 4; ++g)
        bsum[s][g] = b_ih[g * 512 + u] + b_hh[g * 512 + u];
    }
  }

  // staging helper indices: 16 ull per thread per 32KB tile
  #define STAGE_TILE(SRC_EXPR)                                              \
    {                                                                       \
      _Pragma("unroll")                                                     \
      for (int i_ = 0; i_ < 16; ++i_) {                                     \
        int p_ = i_ * 256 + tid;                                            \
        int row_ = p_ >> 6, cu_ = p_ & 63;                                  \
        unsigned long long v_ = (SRC_EXPR);                                 \
        reinterpret_cast<unsigned long long*>(sB)[(row_ * 64 + cu_) ^ ((row_ & 7) << 1)] = v_; \
      }                                                                     \
    }

  #define MFMA_SEG(APTR)                                                    \
    {                                                                       \
      const unsigned short* Ap_ = (APTR);                                   \
      _Pragma("unroll")                                                     \
      for (int kc = 0; kc < 256; kc += 32) {                                \
        short8 a_ = ld8(Ap_ + kc);                                          \
        _Pragma("unroll")                                                   \
        for (int nt = 0; nt < 4; ++nt) {                                    \
          int row_ = l15 + nt * 16;                                         \
          short8 bf_ = *reinterpret_cast<const short8*>(                    \
              sB + ((row_ * 256 + q * 8 + kc) ^ ((row_ & 7) << 3)));        \
          acc[nt] = __builtin_amdgcn_mfma_f32_16x16x32_bf16(a_, bf_, acc[nt], 0, 0, 0); \
        }                                                                   \
      }                                                                     \
    }

  for (int t = 0; t < 20; ++t) {
    unsigned int* hin_u  = (t & 1) ? h1_u : h0_u;
    unsigned int* hout_u = (t & 1) ? h0_u : h1_u;

    // ---- wait for h(t-1) ----
    if (t > 0) {
      if (tid < 32) {
        while ((int)AT_LD(hf + tid) < t) __builtin_amdgcn_s_sleep(1);
      }
      __syncthreads();
      CFENCE();
    }

    // ================= attention (block = batch bid) =================
    {
      const int b = bid;
      unsigned int hv = AT_LD(hin_u + b * 256 + tid);
      sH[2 * tid]     = bf2f((unsigned short)(hv & 0xffffu));
      sH[2 * tid + 1] = bf2f((unsigned short)(hv >> 16));
      __syncthreads();

      // tvec = att_wt(bf16) @ h + att_bt : 2 rows per thread
      {
        const unsigned short* w0 = atwt + (size_t)tid * 512;
        const unsigned short* w1 = w0 + (size_t)256 * 512;
        float a0 = 0.f, a1 = 0.f;
        #pragma unroll 2
        for (int k = 0; k < 512; k += 8) {
          short8 x0 = ld8(w0 + k);
          short8 x1 = ld8(w1 + k);
          #pragma unroll
          for (int j = 0; j < 8; ++j) {
            float hk = sH[k + j];
            a0 += bf2f((unsigned short)x0[j]) * hk;
            a1 += bf2f((unsigned short)x1[j]) * hk;
          }
        }
        sT[tid]       = a0 + att_bt[tid];
        sT[tid + 256] = a1 + att_bt[tid + 256];
      }
      __syncthreads();

      // scores: 16 threads per region; k = i*16+l16 (bank-conflict-free, coalesced)
      {
        int r = tid >> 4, l16 = tid & 15;
        const unsigned short* vp = vproj + ((size_t)b * 16 + r) * 512;
        float s = 0.0f;
        #pragma unroll 4
        for (int i = 0; i < 32; ++i) {
          int k = i * 16 + l16;
          s += tanh_fast(bf2f(vp[k]) + sT[k]) * att_wa[k];
        }
        for (int d = 8; d >= 1; d >>= 1) s += __shfl_down(s, d, 16);
        if (l16 == 0) sSc[r] = s + att_ba[0];
      }
      __syncthreads();

      if (tid < 16) {
        float s = sSc[tid];
        float m = s;
        for (int d = 8; d >= 1; d >>= 1) m = fmaxf(m, __shfl_xor(m, d, 16));
        float e = __expf(s - m);
        float sum = e;
        for (int d = 8; d >= 1; d >>= 1) sum += __shfl_xor(sum, d, 16);
        sAw[tid] = e / sum;
      }
      __syncthreads();

      {
        float a = 0.0f;
        #pragma unroll
        for (int r = 0; r < 16; r++)
          a += sAw[r] * bf2f(visE[((size_t)b * 16 + r) * 256 + tid]);
        sA[tid] = a;
      }
      __syncthreads();

      if (tid < 128) {
        AT_ST(xin_u + b * 128 + tid,
              (unsigned int)f2bf(sA[2 * tid]) | ((unsigned int)f2bf(sA[2 * tid + 1]) << 16));
      }
      WAITCNT0();
      __syncthreads();
      if (tid == 0) AT_ST(xf + bid, (unsigned int)(t + 1));
    }

    // ================= LSTM (blocks 0..31) =================
    if (bid < 32) {
      floatx4 acc[4];
      #pragma unroll
      for (int nt = 0; nt < 4; nt++) acc[nt] = (floatx4){0.f, 0.f, 0.f, 0.f};

      // seg 1: word-embedding half of xin, from read-only emb (cached, no coherence)
      {
        #pragma unroll
        for (int i_ = 0; i_ < 16; ++i_) {
          int p_ = i_ * 256 + tid;
          int row_ = p_ >> 6, c4_ = p_ & 63;
          int cap_ = captions[row_ * 20 + t];
          float4 ev = *reinterpret_cast<const float4*>(emb + (size_t)cap_ * 256 + c4_ * 4);
          unsigned long long v_ =
              (unsigned long long)f2bf(ev.x) |
              ((unsigned long long)f2bf(ev.y) << 16) |
              ((unsigned long long)f2bf(ev.z) << 32) |
              ((unsigned long long)f2bf(ev.w) << 48);
          reinterpret_cast<unsigned long long*>(sB)[(row_ * 64 + c4_) ^ ((row_ & 7) << 1)] = v_;
        }
      }
      __syncthreads();
      MFMA_SEG(wihRow + q * 8);           // w_ih[:, 0:256] @ embed
      __syncthreads();

      // seg 2+3: h(t-1), two 32KB halves (bypass loads)
      const unsigned long long* hull = reinterpret_cast<const unsigned long long*>(hin_u);
      STAGE_TILE(AT_LD(hull + ((i_ * 256 + tid) >> 6) * 128 + ((i_ * 256 + tid) & 63)));
      __syncthreads();
      MFMA_SEG(whhRow + q * 8);           // w_hh[:, 0:256]
      __syncthreads();
      STAGE_TILE(AT_LD(hull + ((i_ * 256 + tid) >> 6) * 128 + 64 + ((i_ * 256 + tid) & 63)));
      __syncthreads();
      MFMA_SEG(whhRow + 256 + q * 8);     // w_hh[:, 256:512]
      __syncthreads();

      // ---- wait for attended halves from all 64 attn blocks ----
      if (tid < 64) {
        while ((int)AT_LD(xf + tid) < t + 1) __builtin_amdgcn_s_sleep(1);
      }
      __syncthreads();
      CFENCE();

      // seg 4: attended half (bypass)
      const unsigned long long* xull = reinterpret_cast<const unsigned long long*>(xin_u);
      STAGE_TILE(AT_LD(xull + ((i_ * 256 + tid) >> 6) * 64 + ((i_ * 256 + tid) & 63)));
      __syncthreads();
      MFMA_SEG(wihRow + 256 + q * 8);     // w_ih[:, 256:512] @ attended
      __syncthreads();

      #pragma unroll
      for (int nt = 0; nt < 4; nt++)
        #pragma unroll
        for (int r = 0; r < 4; r++)
          sG[w][q * 4 + r][nt * 16 + l15] = acc[nt][r];
      __syncthreads();

      const int batch = tid & 63;
      const int g0 = tid >> 6;
      #pragma unroll
      for (int s = 0; s < 4; s += 2) {
        float hn2[2];
        #pragma unroll
        for (int d = 0; d < 2; ++d) {
          int um = g0 * 4 + s + d;
          float ii = sG[0][um][batch] + bsum[s + d][0];
          float ff = sG[1][um][batch] + bsum[s + d][1];
          float gg = sG[2][um][batch] + bsum[s + d][2];
          float oo = sG[3][um][batch] + bsum[s + d][3];
          float cn = sigmoidf_(ff) * creg[s + d] + sigmoidf_(ii) * tanh_fast(gg);
          hn2[d] = sigmoidf_(oo) * tanh_fast(cn);
          creg[s + d] = cn;
        }
        int u = u0 + g0 * 4 + s;
        unsigned int hp = (unsigned int)f2bf(hn2[0]) | ((unsigned int)f2bf(hn2[1]) << 16);
        AT_ST(hout_u + batch * 256 + (u >> 1), hp);
        *reinterpret_cast<unsigned int*>(hs + ((size_t)batch * 20 + t) * 512 + u) = hp;
      }
      WAITCNT0();
      __syncthreads();
      if (tid == 0) AT_ST(hf + bid, (unsigned int)(t + 1));
    }
  }
  #undef STAGE_TILE
  #undef MFMA_SEG
}

// ---------- launch ----------
extern "C" void kernel_launch(void* const* d_in, const int* in_sizes, int n_in,
                              void* d_out, int out_size, void* d_ws, size_t ws_size,
                              hipStream_t stream)
{
  const float* images   = (const float*)d_in[0];
  const int*   captions = (const int*)d_in[1];
  const float* cw[4] = {(const float*)d_in[2],  (const float*)d_in[8],
                        (const float*)d_in[14], (const float*)d_in[20]};
  const float* cbp[4] = {(const float*)d_in[3],  (const float*)d_in[9],
                         (const float*)d_in[15], (const float*)d_in[21]};
  const float* bgp[4] = {(const float*)d_in[4],  (const float*)d_in[10],
                         (const float*)d_in[16], (const float*)d_in[22]};
  const float* bbp[4] = {(const float*)d_in[5],  (const float*)d_in[11],
                         (const float*)d_in[17], (const float*)d_in[23]};
  const float* bmp[4] = {(const float*)d_in[6],  (const float*)d_in[12],
                         (const float*)d_in[18], (const float*)d_in[24]};
  const float* bvp[4] = {(const float*)d_in[7],  (const float*)d_in[13],
                         (const float*)d_in[19], (const float*)d_in[25]};
  const float* proj_w = (const float*)d_in[26];
  const float* proj_b = (const float*)d_in[27];
  const float* emb    = (const float*)d_in[28];
  const float* att_wv = (const float*)d_in[29];
  const float* att_bv = (const float*)d_in[30];
  const float* att_wt = (const float*)d_in[31];
  const float* att_bt = (const float*)d_in[32];
  const float* att_wa = (const float*)d_in[33];
  const float* att_ba = (const float*)d_in[34];
  const float* w_ih   = (const float*)d_in[35];
  const float* w_hh   = (const float*)d_in[36];
  const float* b_ih   = (const float*)d_in[37];
  const float* b_hh   = (const float*)d_in[38];
  const float* out_w  = (const float*)d_in[39];
  const float* out_b  = (const float*)d_in[40];

  char* W = (char*)d_ws;
  unsigned short* wih_b = (unsigned short*)(W + OFF_WIH);
  unsigned short* whh_b = (unsigned short*)(W + OFF_WHH);
  unsigned short* vproj = (unsigned short*)(W + OFF_VPROJ);
  unsigned short* visE  = (unsigned short*)(W + OFF_VISE);
  unsigned short* hs    = (unsigned short*)(W + OFF_HS);
  unsigned short* xin   = (unsigned short*)(W + OFF_XIN);
  unsigned short* h0    = (unsigned short*)(W + OFF_H0);
  unsigned short* h1    = (unsigned short*)(W + OFF_H1);
  unsigned short* w1pad = (unsigned short*)(W + OFF_W1PAD);
  unsigned short* cw2_b = (unsigned short*)(W + OFF_CW2);
  unsigned short* cw3_b = (unsigned short*)(W + OFF_CW3);
  unsigned short* cw4_b = (unsigned short*)(W + OFF_CW4);
  unsigned short* prw_b = (unsigned short*)(W + OFF_PRJW);
  unsigned short* awv_b = (unsigned short*)(W + OFF_ATWV);
  unsigned short* atwt_b= (unsigned short*)(W + OFF_ATWT);
  unsigned short* act1  = (unsigned short*)(W + OFF_ACT1);
  unsigned short* act2  = (unsigned short*)(W + OFF_ACT2);
  unsigned short* act3  = (unsigned short*)(W + OFF_ACT3);
  unsigned short* act4  = (unsigned short*)(W + OFF_ACT4);
  unsigned short* visA  = (unsigned short*)(W + OFF_VISA);
  unsigned short* col   = (unsigned short*)(W + OFF_COL);
  unsigned int*   bar   = (unsigned int*)(W + OFF_BAR);
  const bool big = (ws_size >= NEED_BIG);
  unsigned short* colb  = big ? (unsigned short*)(W + OFF_BIG) : col;

  init_k<<<128, 256, 0, stream>>>(cw[0], w1pad, h0, bar);

  // fused weight conversions f32 -> bf16
  {
    CvtArgs ca;
    ca.s[0] = w_ih;   ca.d[0] = wih_b;
    ca.s[1] = w_hh;   ca.d[1] = whh_b;
    ca.s[2] = cw[1];  ca.d[2] = cw2_b;
    ca.s[3] = cw[2];  ca.d[3] = cw3_b;
    ca.s[4] = cw[3];  ca.d[4] = cw4_b;
    ca.s[5] = proj_w; ca.d[5] = prw_b;
    ca.s[6] = att_wv; ca.d[6] = awv_b;
    ca.s[7] = att_wt; ca.d[7] = atwt_b;
    int c0 = 0;
    int cnt[8] = {262144, 262144, 18432, 73728, 294912, 32768, 32768, 65536};
    ca.cum[0] = 0;
    for (int i = 0; i < 8; i++) { c0 += cnt[i]; ca.cum[i + 1] = c0; }
    cvtall_k<<<(c0 + 255) / 256, 256, 0, stream>>>(ca);
  }

  // conv1: (64,3,64,64) -> (64,64,32,32)
  im2col1_k<<<8192, 256, 0, stream>>>(images, col);
  gemm_k<0><<<dim3(256, 1), 256, 0, stream>>>(w1pad, col, 32, 65536, act1,
      cbp[0], bgp[0], bbp[0], bmp[0], bvp[0], 64, 10, nullptr, 0, 0);

  if (big) {
    im2col_k<<<16384, 256, 0, stream>>>(act1, colb, 64, 32, 32, 576, 576, 8, 4, 0);
    gemm_k<0><<<dim3(64, 2), 256, 0, stream>>>(cw2_b, colb, 576, 16384, act2,
        cbp[1], bgp[1], bbp[1], bmp[1], bvp[1], 128, 8, nullptr, 0, 0);
    im2col_k<<<4096, 256, 0, stream>>>(act2, colb, 128, 16, 16, 1152, 1152, 6, 3, 0);
    gemm_k<0><<<dim3(16, 4), 256, 0, stream>>>(cw3_b, colb, 1152, 4096, act3,
        cbp[2], bgp[2], bbp[2], bmp[2], bvp[2], 256, 6, nullptr, 0, 0);
  } else {
    for (int c = 0; c < 4; c++) {
      im2col_k<<<4096, 256, 0, stream>>>(act1, col, 64, 32, 32, 576, 576, 8, 4, c * 4096);
      gemm_k<0><<<dim3(16, 2), 256, 0, stream>>>(cw2_b, col, 576, 4096, act2,
          cbp[1], bgp[1], bbp[1], bmp[1], bvp[1], 128, 8, nullptr, c * 4096, 0);
    }
    for (int c = 0; c < 2; c++) {
      im2col_k<<<2048, 256, 0, stream>>>(act2, col, 128, 16, 16, 1152, 1152, 6, 3, c * 2048);
      gemm_k<0><<<dim3(8, 4), 256, 0, stream>>>(cw3_b, col, 1152, 2048, act3,
          cbp[2], bgp[2], bbp[2], bmp[2], bvp[2], 256, 6, nullptr, c * 2048, 0);
    }
  }
  // conv4: -> (64,512,4,4); act4 overlays act2
  im2col_k<<<1024, 256, 0, stream>>>(act3, col, 256, 8, 8, 2304, 2304, 4, 2, 0);
  gemm_k<0><<<dim3(4, 8), 256, 0, stream>>>(cw4_b, col, 2304, 1024, act4,
      cbp[3], bgp[3], bbp[3], bmp[3], bvp[3], 512, 4, nullptr, 0, 0);

  // visual gather + projections
  visa_k<<<2048, 256, 0, stream>>>(act4, visA);
  gemm_k<1><<<dim3(1, 16), 256, 0, stream>>>(visA, prw_b, 512, 256, visE,
      nullptr, nullptr, nullptr, nullptr, nullptr, 0, 0, proj_b, 0, 0);
  gemm_k<1><<<dim3(2, 16), 256, 0, stream>>>(visE, awv_b, 256, 512, vproj,
      nullptr, nullptr, nullptr, nullptr, nullptr, 0, 0, att_bv, 0, 0);

  // fused 20-step recurrence
  rec_k<<<64, 256, 0, stream>>>(wih_b, whh_b, b_ih, b_hh, vproj, visE,
                                atwt_b, att_bt, att_wa, att_ba, captions, emb,
                                (unsigned int*)xin, (unsigned int*)h0, (unsigned int*)h1,
                                hs, bar);

  // logits: (1280,512) x (32000,512)^T -> d_out f32 (B,T,V)
  if (big) {
    unsigned short* owb = (unsigned short*)(W + OFF_BIG);
    cvt_k<<<16000, 256, 0, stream>>>(out_w, owb, 32000 * 512 / 4);
    gemm_k<2><<<dim3(125, 20), 256, 0, stream>>>(hs, owb, 512, 32000,
        d_out, nullptr, nullptr, nullptr, nullptr, nullptr, 0, 0, out_b, 0, 32000);
  } else {
    for (int c = 0; c < 8; c++) {
      int rows = (c < 7) ? 4096 : 3328;
      const float* src = out_w + (size_t)c * 4096 * 512;
      cvt_k<<<rows / 2, 256, 0, stream>>>(src, col, rows * 512 / 4);
      gemm_k<2><<<dim3(rows / 256, 20), 256, 0, stream>>>(hs, col, 512, rows,
          d_out, nullptr, nullptr, nullptr, nullptr, nullptr, 0, 0, out_b, c * 4096, 32000);
    }
  }
}

// Round 4
// 1551.094 us; speedup vs baseline: 1.5484x; 1.0874x over previous
//
#include <hip/hip_runtime.h>
#include <hip/hip_bf16.h>
#include <cstdint>
#include <cstddef>

// ---------- types / helpers ----------
typedef __attribute__((ext_vector_type(8))) short short8;   // 8 x bf16 (4 VGPRs)
typedef __attribute__((ext_vector_type(4))) float floatx4;  // mfma accumulator

__device__ inline float bf2f(unsigned short u) {
  union { unsigned int i; float f; } v; v.i = ((unsigned int)u) << 16; return v.f;
}
__device__ inline unsigned short f2bf(float f) {
  union { float f; unsigned int i; } v; v.f = f;
  unsigned int u = v.i;
  return (unsigned short)((u + 0x7FFFu + ((u >> 16) & 1u)) >> 16); // RNE
}
__device__ inline short8 ld8(const unsigned short* p) {
  return *reinterpret_cast<const short8*>(p); // 16B aligned everywhere we use it
}
__device__ inline float sigmoidf_(float x) { return 1.0f / (1.0f + __expf(-x)); }
__device__ inline float tanh_fast(float x) {
  float e = __expf(2.0f * x);
  return 1.0f - 2.0f / (e + 1.0f);   // exact at saturation
}

// bypass (device-coherent) ops: ONLY for flags (polled) and producer stores.
#define AT_LD(p)    __hip_atomic_load((p), __ATOMIC_RELAXED, __HIP_MEMORY_SCOPE_AGENT)
#define AT_ST(p, v) __hip_atomic_store((p), (v), __ATOMIC_RELAXED, __HIP_MEMORY_SCOPE_AGENT)
#define WAITCNT0()  asm volatile("s_waitcnt vmcnt(0) lgkmcnt(0)" ::: "memory")
#define CFENCE()    asm volatile("" ::: "memory")

// ---------- workspace layout (bytes) ----------
static const size_t OFF_WIH   = 0;          // 2,097,152  bf16 w_ih (2048,512)
static const size_t OFF_WHH   = 2097152;    // 2,097,152  bf16 w_hh (2048,512)
static const size_t OFF_VPROJ = 4194304;    // 1,048,576  bf16 (1024,512)
static const size_t OFF_VISE  = 5242880;    //   524,288  bf16 (1024,256)
static const size_t OFF_HS    = 5767168;    // 1,310,720  bf16 (1280,512) row=b*20+t
static const size_t OFF_W1PAD = 7405568;    //     4,096  bf16 (64,32)
static const size_t OFF_CW2   = 7409664;    //   147,456  bf16 (128,576)
static const size_t OFF_CW3   = 7557120;    //   589,824  bf16 (256,1152)
static const size_t OFF_CW4   = 8146944;    // 2,359,296  bf16 (512,2304)
static const size_t OFF_PRJW  = 10506240;   //   262,144  bf16 (256,512)
static const size_t OFF_ATWV  = 10768384;   //   262,144  bf16 (512,256)
static const size_t OFF_ACT1  = 11030528;   // 8,388,608  bf16 (64,64,32,32); act3 reuses
static const size_t OFF_ACT3  = 11030528;   // 2,097,152  bf16 (64,256,8,8)
static const size_t OFF_ACT2  = 19419136;   // 4,194,304  bf16 (64,128,16,16); act4/visA/rot reuse
static const size_t OFF_ACT4  = 19419136;   // 1,048,576  bf16 (64,512,4,4)
static const size_t OFF_VISA  = 20467712;   // 1,048,576  bf16 (1024,512)
// rotating recurrence buffers live in the dead tail of the act2 arena
// (written by conv2-gemm, last read by conv3-im2col; dead before visa_k/rec_k)
static const size_t OFF_XB    = 21516288;   //   655,360  20 x 32KB attended (bf16 64x256)
static const size_t OFF_HB    = 22171648;   // 1,310,720  20 x 64KB h_t (bf16 64x512), slot t
static const size_t OFF_FLG   = 23482368;   //    10,240  20 x 128 uint flags (xf[64], hf[32])
static const size_t OFF_COL   = 23613440;   // 4,718,592  small im2col arena / out_w chunks
static const size_t OFF_ATWT  = 28348416;   //   524,288  bf16 att_wt (512,512)
static const size_t OFF_BIG   = 28872704;   // optional: 32,768,000 big arena
static const size_t NEED_BIG  = OFF_BIG + 32768000; // 61,640,704

// ---------- f32 -> bf16 bulk convert (4 elems/thread) ----------
__global__ void cvt_k(const float* __restrict__ s, unsigned short* __restrict__ d, int n4)
{
  int i = blockIdx.x * 256 + threadIdx.x;
  if (i < n4) {
    float4 v = reinterpret_cast<const float4*>(s)[i];
    ushort4 o;
    o.x = f2bf(v.x); o.y = f2bf(v.y); o.z = f2bf(v.z); o.w = f2bf(v.w);
    reinterpret_cast<ushort4*>(d)[i] = o;
  }
}

// ---------- fused multi-segment f32 -> bf16 convert (8 tensors, one dispatch) ----------
struct CvtArgs {
  const float* s[8];
  unsigned short* d[8];
  int cum[9];  // cumulative float4 counts, cum[0]=0
};
__global__ void cvtall_k(CvtArgs a)
{
  int i = blockIdx.x * 256 + threadIdx.x;
  if (i >= a.cum[8]) return;
  int seg = 0;
  while (seg < 7 && i >= a.cum[seg + 1]) ++seg;
  int j = i - a.cum[seg];
  float4 v = reinterpret_cast<const float4*>(a.s[seg])[j];
  ushort4 o;
  o.x = f2bf(v.x); o.y = f2bf(v.y); o.z = f2bf(v.z); o.w = f2bf(v.w);
  reinterpret_cast<ushort4*>(a.d[seg])[j] = o;
}

// ---------- init: conv1 weight K-pad (f32->bf16) ----------
__global__ void init_k(const float* __restrict__ conv1_w, unsigned short* __restrict__ w1pad)
{
  int i = blockIdx.x * 256 + threadIdx.x;               // grid covers 2048
  if (i < 64 * 32) {
    int co = i >> 5, k = i & 31;
    w1pad[i] = (k < 27) ? f2bf(conv1_w[co * 27 + k]) : (unsigned short)0;
  }
}

// ---------- conv1 im2col ----------
__global__ void im2col1_k(const float* __restrict__ in, unsigned short* __restrict__ col)
{
  int o = blockIdx.x * 256 + threadIdx.x;   // 65536 pixels * 32 Kpad = 2,097,152
  int n = o >> 5, k = o & 31;
  unsigned short v = 0;
  if (k < 27) {
    int b = n >> 10, y = (n >> 5) & 31, x = n & 31;
    int ci = k / 9, r9 = k - ci * 9, ky = r9 / 3, kx = r9 - ky * 3;
    int iy = 2 * y - 1 + ky, ix = 2 * x - 1 + kx;
    if (iy >= 0 && iy < 64 && ix >= 0 && ix < 64)
      v = f2bf(in[(((size_t)b * 3 + ci) << 12) + (iy << 6) + ix]);
  }
  col[o] = v;
}

// ---------- im2col (chunked) ----------
__global__ void im2col_k(const unsigned short* __restrict__ in, unsigned short* __restrict__ col,
                         int Cin, int Hin, int Win, int Kreal, int Kpad, int lgHW, int lgW,
                         int n0)
{
  const int ng = n0 + blockIdx.x;
  const int b = ng >> lgHW;
  const int yx = ng & ((1 << lgHW) - 1);
  const int y = yx >> lgW;
  const int x = yx & ((1 << lgW) - 1);
  const int iy0 = 2 * y - 1;
  const int ix0 = 2 * x - 1;
  for (int k = threadIdx.x; k < Kpad; k += blockDim.x) {
    unsigned short v = 0;
    if (k < Kreal) {
      int ci = k / 9;
      int r9 = k - ci * 9;
      int ky = r9 / 3;
      int kx = r9 - ky * 3;
      int iy = iy0 + ky, ix = ix0 + kx;
      if (iy >= 0 && iy < Hin && ix >= 0 && ix < Win) {
        size_t idx = (((size_t)b * Cin + ci) * Hin + iy) * Win + ix;
        v = in[idx];
      }
    }
    col[(size_t)blockIdx.x * Kpad + k] = v;
  }
}

// ---------- gather visual + zero recurrence flags (bypass stores) ----------
__global__ void visa_k(const unsigned short* __restrict__ act4, unsigned short* __restrict__ visA,
                       unsigned int* __restrict__ flg)
{
  int o = blockIdx.x * 256 + threadIdx.x;   // 524288 total
  int c = o & 511, br = o >> 9;
  int b = br >> 4, r = br & 15;
  visA[o] = act4[(((size_t)b * 512 + c) << 4) + r];
  if (o < 2560) AT_ST(flg + o, 0u);         // 20 steps x 128 flags
}

// ---------- generic MFMA GEMM: C(M,N) = A(M,K) * B(N,K)^T, A/B bf16 ----------
template<int EPI>
__global__ __launch_bounds__(256)
void gemm_k(const unsigned short* __restrict__ A, const unsigned short* __restrict__ B,
            int K, int N, void* __restrict__ outp,
            const float* __restrict__ cb, const float* __restrict__ bg,
            const float* __restrict__ bb, const float* __restrict__ bm,
            const float* __restrict__ bv, int Cout, int lgHW,
            const float* __restrict__ biasN, int n_base, int ldOut)
{
  const int w   = threadIdx.x >> 6;
  const int l   = threadIdx.x & 63;
  const int l15 = l & 15;
  const int q   = l >> 4;
  const int m0  = blockIdx.y * 64;
  const int n0  = blockIdx.x * 256 + w * 64;
  const unsigned short* Ap = A + (size_t)(m0 + l15) * K + q * 8;
  const unsigned short* Bp = B + (size_t)(n0 + l15) * K + q * 8;

  floatx4 acc[4][4];
  #pragma unroll
  for (int i = 0; i < 4; i++)
    #pragma unroll
    for (int j = 0; j < 4; j++)
      acc[i][j] = (floatx4){0.f, 0.f, 0.f, 0.f};

  for (int kc = 0; kc < K; kc += 32) {
    short8 a0 = ld8(Ap + kc);
    short8 a1 = ld8(Ap + (size_t)16 * K + kc);
    short8 a2 = ld8(Ap + (size_t)32 * K + kc);
    short8 a3 = ld8(Ap + (size_t)48 * K + kc);
    #pragma unroll
    for (int nf = 0; nf < 4; nf++) {
      short8 bf = ld8(Bp + (size_t)(nf * 16) * K + kc);
      acc[0][nf] = __builtin_amdgcn_mfma_f32_16x16x32_bf16(a0, bf, acc[0][nf], 0, 0, 0);
      acc[1][nf] = __builtin_amdgcn_mfma_f32_16x16x32_bf16(a1, bf, acc[1][nf], 0, 0, 0);
      acc[2][nf] = __builtin_amdgcn_mfma_f32_16x16x32_bf16(a2, bf, acc[2][nf], 0, 0, 0);
      acc[3][nf] = __builtin_amdgcn_mfma_f32_16x16x32_bf16(a3, bf, acc[3][nf], 0, 0, 0);
    }
  }
  // C/D layout (verified m89/m91): col = lane&15, row = (lane>>4)*4 + reg
  #pragma unroll
  for (int mf = 0; mf < 4; mf++) {
    #pragma unroll
    for (int r = 0; r < 4; r++) {
      int m = m0 + mf * 16 + q * 4 + r;
      float scale = 1.0f, shift = 0.0f;
      if (EPI == 0) {
        float inv = bg[m] / sqrtf(bv[m] + 1e-5f);
        scale = inv;
        shift = (cb[m] - bm[m]) * inv + bb[m];
      }
      #pragma unroll
      for (int nf = 0; nf < 4; nf++) {
        int n = n0 + nf * 16 + l15;
        float c = acc[mf][nf][r];
        if (EPI == 0) {
          c = fmaxf(c * scale + shift, 0.0f);
          int ng = n_base + n;
          int bi = ng >> lgHW;
          int yx = ng & ((1 << lgHW) - 1);
          ((unsigned short*)outp)[(((size_t)bi * Cout + m) << lgHW) + yx] = f2bf(c);
        } else if (EPI == 1) {
          ((unsigned short*)outp)[(size_t)m * N + n] = f2bf(c + biasN[n]);
        } else {
          ((float*)outp)[(size_t)m * ldOut + n_base + n] = c + biasN[n_base + n];
        }
      }
    }
  }
}

// ---------- fused 20-step recurrence: rotating buffers, normal bulk loads ----------
// grid = 64 blocks x 256 threads, co-resident. Per-step FRESH buffers (slot t) so
// consumers use normal cached loads; producers use bypass stores + vmcnt + flag.
// Atomics only on 4B flags. t=0: h==0 -> skip matvec and h MFMA segments.
__global__ __launch_bounds__(256)
void rec_k(const unsigned short* __restrict__ w_ih, const unsigned short* __restrict__ w_hh,
           const float* __restrict__ b_ih, const float* __restrict__ b_hh,
           const unsigned short* __restrict__ vproj, const unsigned short* __restrict__ visE,
           const unsigned short* __restrict__ atwt, const float* __restrict__ att_bt,
           const float* __restrict__ att_wa, const float* __restrict__ att_ba,
           const int* __restrict__ captions, const float* __restrict__ emb,
           unsigned int* xb, unsigned int* hb, unsigned int* flg,
           unsigned short* __restrict__ hs)
{
  __shared__ __align__(16) float sH[512];
  __shared__ float sT[512];
  __shared__ float sA[256];
  __shared__ float sSc[16];
  __shared__ float sAw[16];
  __shared__ __align__(16) unsigned short sB[64 * 256];  // 32 KB B-tile, XOR-swizzled
  __shared__ float sG[4][16][64];

  const int tid = threadIdx.x;
  const int bid = blockIdx.x;
  const int w   = tid >> 6;
  const int l   = tid & 63;
  const int l15 = l & 15;
  const int q   = l >> 4;
  const int u0  = bid * 16;                 // LSTM unit base (blocks 0..31)
  const int arow = w * 512 + u0 + l15;      // gate-major weight row
  const unsigned short* wihRow = w_ih + (size_t)arow * 512;
  const unsigned short* whhRow = w_hh + (size_t)arow * 512;

  // persistent cell state + bias sums (LSTM blocks only)
  float creg[4];
  float bsum[4][4];   // [s][gate]
  if (bid < 32) {
    const int g0 = tid >> 6;
    #pragma unroll
    for (int s = 0; s < 4; ++s) {
      creg[s] = 0.0f;
      int u = u0 + g0 * 4 + s;
      #pragma unroll
      for (int g = 0; g < 4; ++g)
        bsum[s][g] = b_ih[g * 512 + u] + b_hh[g * 512 + u];
    }
  }

  // normal-load staging: 16 b64 per thread per 32KB tile, XOR-swizzled LDS
  #define STAGE_TILE(SRC_EXPR)                                              \
    {                                                                       \
      _Pragma("unroll")                                                     \
      for (int i_ = 0; i_ < 16; ++i_) {                                     \
        int p_ = i_ * 256 + tid;                                            \
        int row_ = p_ >> 6, cu_ = p_ & 63;                                  \
        unsigned long long v_ = (SRC_EXPR);                                 \
        reinterpret_cast<unsigned long long*>(sB)[(row_ * 64 + cu_) ^ ((row_ & 7) << 1)] = v_; \
      }                                                                     \
    }

  #define MFMA_SEG(APTR)                                                    \
    {                                                                       \
      const unsigned short* Ap_ = (APTR);                                   \
      _Pragma("unroll")                                                     \
      for (int kc = 0; kc < 256; kc += 32) {                                \
        short8 a_ = ld8(Ap_ + kc);                                          \
        _Pragma("unroll")                                                   \
        for (int nt = 0; nt < 4; ++nt) {                                    \
          int row_ = l15 + nt * 16;                                         \
          short8 bf_ = *reinterpret_cast<const short8*>(                    \
              sB + ((row_ * 256 + q * 8 + kc) ^ ((row_ & 7) << 3)));        \
          acc[nt] = __builtin_amdgcn_mfma_f32_16x16x32_bf16(a_, bf_, acc[nt], 0, 0, 0); \
        }                                                                   \
      }                                                                     \
    }

  for (int t = 0; t < 20; ++t) {
    const unsigned int* hbin = hb + (size_t)(t - 1) * 16384;   // valid for t>0
    unsigned int* hbout = hb + (size_t)t * 16384;
    unsigned int* xbt   = xb + (size_t)t * 8192;
    unsigned int* flgt  = flg + (size_t)t * 128;

    // ---- wait for h(t-1) ----
    if (t > 0) {
      if (tid < 32) {
        while (AT_LD(flg + (size_t)(t - 1) * 128 + 64 + tid) == 0u)
          __builtin_amdgcn_s_sleep(1);
      }
      __syncthreads();
      CFENCE();
    }

    // ================= attention (block = batch bid) =================
    {
      const int b = bid;
      if (t > 0) {
        unsigned int hv = hbin[b * 256 + tid];   // normal cached load (fresh addr)
        sH[2 * tid]     = bf2f((unsigned short)(hv & 0xffffu));
        sH[2 * tid + 1] = bf2f((unsigned short)(hv >> 16));
        __syncthreads();

        // tvec = att_wt(bf16) @ h + att_bt : 2 rows per thread
        const unsigned short* w0 = atwt + (size_t)tid * 512;
        const unsigned short* w1 = w0 + (size_t)256 * 512;
        float a0 = 0.f, a1 = 0.f;
        #pragma unroll 2
        for (int k = 0; k < 512; k += 8) {
          short8 x0 = ld8(w0 + k);
          short8 x1 = ld8(w1 + k);
          #pragma unroll
          for (int j = 0; j < 8; ++j) {
            float hk = sH[k + j];
            a0 += bf2f((unsigned short)x0[j]) * hk;
            a1 += bf2f((unsigned short)x1[j]) * hk;
          }
        }
        sT[tid]       = a0 + att_bt[tid];
        sT[tid + 256] = a1 + att_bt[tid + 256];
      } else {
        sT[tid]       = att_bt[tid];      // h==0 -> tvec = bias
        sT[tid + 256] = att_bt[tid + 256];
      }
      __syncthreads();

      // scores: 16 threads per region; k = i*16+l16 (bank-conflict-free)
      {
        int r = tid >> 4, l16 = tid & 15;
        const unsigned short* vp = vproj + ((size_t)b * 16 + r) * 512;
        float s = 0.0f;
        #pragma unroll 4
        for (int i = 0; i < 32; ++i) {
          int k = i * 16 + l16;
          s += tanh_fast(bf2f(vp[k]) + sT[k]) * att_wa[k];
        }
        for (int d = 8; d >= 1; d >>= 1) s += __shfl_down(s, d, 16);
        if (l16 == 0) sSc[r] = s + att_ba[0];
      }
      __syncthreads();

      if (tid < 16) {
        float s = sSc[tid];
        float m = s;
        for (int d = 8; d >= 1; d >>= 1) m = fmaxf(m, __shfl_xor(m, d, 16));
        float e = __expf(s - m);
        float sum = e;
        for (int d = 8; d >= 1; d >>= 1) sum += __shfl_xor(sum, d, 16);
        sAw[tid] = e / sum;
      }
      __syncthreads();

      {
        float a = 0.0f;
        #pragma unroll
        for (int r = 0; r < 16; r++)
          a += sAw[r] * bf2f(visE[((size_t)b * 16 + r) * 256 + tid]);
        sA[tid] = a;
      }
      __syncthreads();

      if (tid < 64) {   // pack 4 bf16 per lane, bypass store through coherent point
        int j = 4 * tid;
        unsigned long long v =
            (unsigned long long)f2bf(sA[j]) |
            ((unsigned long long)f2bf(sA[j + 1]) << 16) |
            ((unsigned long long)f2bf(sA[j + 2]) << 32) |
            ((unsigned long long)f2bf(sA[j + 3]) << 48);
        AT_ST(reinterpret_cast<unsigned long long*>(xbt) + b * 64 + tid, v);
      }
      WAITCNT0();
      __syncthreads();
      if (tid == 0) AT_ST(flgt + bid, 1u);
    }

    // ================= LSTM (blocks 0..31) =================
    if (bid < 32) {
      floatx4 acc[4];
      #pragma unroll
      for (int nt = 0; nt < 4; nt++) acc[nt] = (floatx4){0.f, 0.f, 0.f, 0.f};

      // seg 1: word-embedding half of xin, from read-only emb (cached)
      {
        #pragma unroll
        for (int i_ = 0; i_ < 16; ++i_) {
          int p_ = i_ * 256 + tid;
          int row_ = p_ >> 6, c4_ = p_ & 63;
          int cap_ = captions[row_ * 20 + t];
          float4 ev = *reinterpret_cast<const float4*>(emb + (size_t)cap_ * 256 + c4_ * 4);
          unsigned long long v_ =
              (unsigned long long)f2bf(ev.x) |
              ((unsigned long long)f2bf(ev.y) << 16) |
              ((unsigned long long)f2bf(ev.z) << 32) |
              ((unsigned long long)f2bf(ev.w) << 48);
          reinterpret_cast<unsigned long long*>(sB)[(row_ * 64 + c4_) ^ ((row_ & 7) << 1)] = v_;
        }
      }
      __syncthreads();
      MFMA_SEG(wihRow + q * 8);           // w_ih[:, 0:256] @ embed
      __syncthreads();

      if (t > 0) {
        // seg 2+3: h(t-1), two 32KB halves (NORMAL loads, L3/L2-cacheable)
        const unsigned long long* hull = reinterpret_cast<const unsigned long long*>(hbin);
        STAGE_TILE(hull[((i_ * 256 + tid) >> 6) * 128 + ((i_ * 256 + tid) & 63)]);
        __syncthreads();
        MFMA_SEG(whhRow + q * 8);           // w_hh[:, 0:256]
        __syncthreads();
        STAGE_TILE(hull[((i_ * 256 + tid) >> 6) * 128 + 64 + ((i_ * 256 + tid) & 63)]);
        __syncthreads();
        MFMA_SEG(whhRow + 256 + q * 8);     // w_hh[:, 256:512]
        __syncthreads();
      }

      // ---- wait for attended halves from all 64 attn blocks ----
      if (tid < 64) {
        while (AT_LD(flgt + tid) == 0u) __builtin_amdgcn_s_sleep(1);
      }
      __syncthreads();
      CFENCE();

      // seg 4: attended half (NORMAL loads; fresh addresses, via coherent point)
      const unsigned long long* xull = reinterpret_cast<const unsigned long long*>(xbt);
      STAGE_TILE(xull[((i_ * 256 + tid) >> 6) * 64 + ((i_ * 256 + tid) & 63)]);
      __syncthreads();
      MFMA_SEG(wihRow + 256 + q * 8);     // w_ih[:, 256:512] @ attended
      __syncthreads();

      #pragma unroll
      for (int nt = 0; nt < 4; nt++)
        #pragma unroll
        for (int r = 0; r < 4; r++)
          sG[w][q * 4 + r][nt * 16 + l15] = acc[nt][r];
      __syncthreads();

      const int batch = tid & 63;
      const int g0 = tid >> 6;
      #pragma unroll
      for (int s = 0; s < 4; s += 2) {
        float hn2[2];
        #pragma unroll
        for (int d = 0; d < 2; ++d) {
          int um = g0 * 4 + s + d;
          float ii = sG[0][um][batch] + bsum[s + d][0];
          float ff = sG[1][um][batch] + bsum[s + d][1];
          float gg = sG[2][um][batch] + bsum[s + d][2];
          float oo = sG[3][um][batch] + bsum[s + d][3];
          float cn = sigmoidf_(ff) * creg[s + d] + sigmoidf_(ii) * tanh_fast(gg);
          hn2[d] = sigmoidf_(oo) * tanh_fast(cn);
          creg[s + d] = cn;
        }
        int u = u0 + g0 * 4 + s;
        unsigned int hp = (unsigned int)f2bf(hn2[0]) | ((unsigned int)f2bf(hn2[1]) << 16);
        AT_ST(hbout + batch * 256 + (u >> 1), hp);   // bypass store
        *reinterpret_cast<unsigned int*>(hs + ((size_t)batch * 20 + t) * 512 + u) = hp;
      }
      WAITCNT0();
      __syncthreads();
      if (tid == 0) AT_ST(flgt + 64 + bid, 1u);
    }
  }
  #undef STAGE_TILE
  #undef MFMA_SEG
}

// ---------- launch ----------
extern "C" void kernel_launch(void* const* d_in, const int* in_sizes, int n_in,
                              void* d_out, int out_size, void* d_ws, size_t ws_size,
                              hipStream_t stream)
{
  const float* images   = (const float*)d_in[0];
  const int*   captions = (const int*)d_in[1];
  const float* cw[4] = {(const float*)d_in[2],  (const float*)d_in[8],
                        (const float*)d_in[14], (const float*)d_in[20]};
  const float* cbp[4] = {(const float*)d_in[3],  (const float*)d_in[9],
                         (const float*)d_in[15], (const float*)d_in[21]};
  const float* bgp[4] = {(const float*)d_in[4],  (const float*)d_in[10],
                         (const float*)d_in[16], (const float*)d_in[22]};
  const float* bbp[4] = {(const float*)d_in[5],  (const float*)d_in[11],
                         (const float*)d_in[17], (const float*)d_in[23]};
  const float* bmp[4] = {(const float*)d_in[6],  (const float*)d_in[12],
                         (const float*)d_in[18], (const float*)d_in[24]};
  const float* bvp[4] = {(const float*)d_in[7],  (const float*)d_in[13],
                         (const float*)d_in[19], (const float*)d_in[25]};
  const float* proj_w = (const float*)d_in[26];
  const float* proj_b = (const float*)d_in[27];
  const float* emb    = (const float*)d_in[28];
  const float* att_wv = (const float*)d_in[29];
  const float* att_bv = (const float*)d_in[30];
  const float* att_wt = (const float*)d_in[31];
  const float* att_bt = (const float*)d_in[32];
  const float* att_wa = (const float*)d_in[33];
  const float* att_ba = (const float*)d_in[34];
  const float* w_ih   = (const float*)d_in[35];
  const float* w_hh   = (const float*)d_in[36];
  const float* b_ih   = (const float*)d_in[37];
  const float* b_hh   = (const float*)d_in[38];
  const float* out_w  = (const float*)d_in[39];
  const float* out_b  = (const float*)d_in[40];

  char* W = (char*)d_ws;
  unsigned short* wih_b = (unsigned short*)(W + OFF_WIH);
  unsigned short* whh_b = (unsigned short*)(W + OFF_WHH);
  unsigned short* vproj = (unsigned short*)(W + OFF_VPROJ);
  unsigned short* visE  = (unsigned short*)(W + OFF_VISE);
  unsigned short* hs    = (unsigned short*)(W + OFF_HS);
  unsigned short* w1pad = (unsigned short*)(W + OFF_W1PAD);
  unsigned short* cw2_b = (unsigned short*)(W + OFF_CW2);
  unsigned short* cw3_b = (unsigned short*)(W + OFF_CW3);
  unsigned short* cw4_b = (unsigned short*)(W + OFF_CW4);
  unsigned short* prw_b = (unsigned short*)(W + OFF_PRJW);
  unsigned short* awv_b = (unsigned short*)(W + OFF_ATWV);
  unsigned short* atwt_b= (unsigned short*)(W + OFF_ATWT);
  unsigned short* act1  = (unsigned short*)(W + OFF_ACT1);
  unsigned short* act2  = (unsigned short*)(W + OFF_ACT2);
  unsigned short* act3  = (unsigned short*)(W + OFF_ACT3);
  unsigned short* act4  = (unsigned short*)(W + OFF_ACT4);
  unsigned short* visA  = (unsigned short*)(W + OFF_VISA);
  unsigned short* col   = (unsigned short*)(W + OFF_COL);
  unsigned int*   xbp   = (unsigned int*)(W + OFF_XB);
  unsigned int*   hbp   = (unsigned int*)(W + OFF_HB);
  unsigned int*   flg   = (unsigned int*)(W + OFF_FLG);
  const bool big = (ws_size >= NEED_BIG);
  unsigned short* colb  = big ? (unsigned short*)(W + OFF_BIG) : col;

  init_k<<<8, 256, 0, stream>>>(cw[0], w1pad);

  // fused weight conversions f32 -> bf16
  {
    CvtArgs ca;
    ca.s[0] = w_ih;   ca.d[0] = wih_b;
    ca.s[1] = w_hh;   ca.d[1] = whh_b;
    ca.s[2] = cw[1];  ca.d[2] = cw2_b;
    ca.s[3] = cw[2];  ca.d[3] = cw3_b;
    ca.s[4] = cw[3];  ca.d[4] = cw4_b;
    ca.s[5] = proj_w; ca.d[5] = prw_b;
    ca.s[6] = att_wv; ca.d[6] = awv_b;
    ca.s[7] = att_wt; ca.d[7] = atwt_b;
    int c0 = 0;
    int cnt[8] = {262144, 262144, 18432, 73728, 294912, 32768, 32768, 65536};
    ca.cum[0] = 0;
    for (int i = 0; i < 8; i++) { c0 += cnt[i]; ca.cum[i + 1] = c0; }
    cvtall_k<<<(c0 + 255) / 256, 256, 0, stream>>>(ca);
  }

  // conv1: (64,3,64,64) -> (64,64,32,32)
  im2col1_k<<<8192, 256, 0, stream>>>(images, col);
  gemm_k<0><<<dim3(256, 1), 256, 0, stream>>>(w1pad, col, 32, 65536, act1,
      cbp[0], bgp[0], bbp[0], bmp[0], bvp[0], 64, 10, nullptr, 0, 0);

  if (big) {
    im2col_k<<<16384, 256, 0, stream>>>(act1, colb, 64, 32, 32, 576, 576, 8, 4, 0);
    gemm_k<0><<<dim3(64, 2), 256, 0, stream>>>(cw2_b, colb, 576, 16384, act2,
        cbp[1], bgp[1], bbp[1], bmp[1], bvp[1], 128, 8, nullptr, 0, 0);
    im2col_k<<<4096, 256, 0, stream>>>(act2, colb, 128, 16, 16, 1152, 1152, 6, 3, 0);
    gemm_k<0><<<dim3(16, 4), 256, 0, stream>>>(cw3_b, colb, 1152, 4096, act3,
        cbp[2], bgp[2], bbp[2], bmp[2], bvp[2], 256, 6, nullptr, 0, 0);
  } else {
    for (int c = 0; c < 4; c++) {
      im2col_k<<<4096, 256, 0, stream>>>(act1, col, 64, 32, 32, 576, 576, 8, 4, c * 4096);
      gemm_k<0><<<dim3(16, 2), 256, 0, stream>>>(cw2_b, col, 576, 4096, act2,
          cbp[1], bgp[1], bbp[1], bmp[1], bvp[1], 128, 8, nullptr, c * 4096, 0);
    }
    for (int c = 0; c < 2; c++) {
      im2col_k<<<2048, 256, 0, stream>>>(act2, col, 128, 16, 16, 1152, 1152, 6, 3, c * 2048);
      gemm_k<0><<<dim3(8, 4), 256, 0, stream>>>(cw3_b, col, 1152, 2048, act3,
          cbp[2], bgp[2], bbp[2], bmp[2], bvp[2], 256, 6, nullptr, c * 2048, 0);
    }
  }
  // conv4: -> (64,512,4,4); act4 overlays act2
  im2col_k<<<1024, 256, 0, stream>>>(act3, col, 256, 8, 8, 2304, 2304, 4, 2, 0);
  gemm_k<0><<<dim3(4, 8), 256, 0, stream>>>(cw4_b, col, 2304, 1024, act4,
      cbp[3], bgp[3], bbp[3], bmp[3], bvp[3], 512, 4, nullptr, 0, 0);

  // visual gather (+ flag zeroing) + projections
  visa_k<<<2048, 256, 0, stream>>>(act4, visA, flg);
  gemm_k<1><<<dim3(1, 16), 256, 0, stream>>>(visA, prw_b, 512, 256, visE,
      nullptr, nullptr, nullptr, nullptr, nullptr, 0, 0, proj_b, 0, 0);
  gemm_k<1><<<dim3(2, 16), 256, 0, stream>>>(visE, awv_b, 256, 512, vproj,
      nullptr, nullptr, nullptr, nullptr, nullptr, 0, 0, att_bv, 0, 0);

  // fused 20-step recurrence
  rec_k<<<64, 256, 0, stream>>>(wih_b, whh_b, b_ih, b_hh, vproj, visE,
                                atwt_b, att_bt, att_wa, att_ba, captions, emb,
                                xbp, hbp, flg, hs);

  // logits: (1280,512) x (32000,512)^T -> d_out f32 (B,T,V)
  if (big) {
    unsigned short* owb = (unsigned short*)(W + OFF_BIG);
    cvt_k<<<16000, 256, 0, stream>>>(out_w, owb, 32000 * 512 / 4);
    gemm_k<2><<<dim3(125, 20), 256, 0, stream>>>(hs, owb, 512, 32000,
        d_out, nullptr, nullptr, nullptr, nullptr, nullptr, 0, 0, out_b, 0, 32000);
  } else {
    for (int c = 0; c < 8; c++) {
      int rows = (c < 7) ? 4096 : 3328;
      const float* src = out_w + (size_t)c * 4096 * 512;
      cvt_k<<<rows / 2, 256, 0, stream>>>(src, col, rows * 512 / 4);
      gemm_k<2><<<dim3(rows / 256, 20), 256, 0, stream>>>(hs, col, 512, rows,
          d_out, nullptr, nullptr, nullptr, nullptr, nullptr, 0, 0, out_b, c * 4096, 32000);
    }
  }
}